// Round 14
// baseline (630.450 us; speedup 1.0000x reference)
//
#include <hip/hip_runtime.h>

#define Bb 4
#define Nn 4096
#define Dd 256
#define Hh 4
#define HDd 64
#define FFf 512
#define MT 16384  // B*N

typedef __attribute__((ext_vector_type(8))) short short8;
typedef __attribute__((ext_vector_type(4))) float f32x4;
typedef __attribute__((ext_vector_type(16))) float f32x16;
typedef unsigned short u16;
typedef unsigned int u32;
typedef __attribute__((ext_vector_type(4))) u32 u32x4;

typedef __attribute__((address_space(1))) const void glb_src;
typedef __attribute__((address_space(3))) void lds_dst;

__device__ __forceinline__ void gload_lds16(const void* g, void* l) {
    __builtin_amdgcn_global_load_lds((glb_src*)g, (lds_dst*)l, 16, 0, 0);
}

__device__ __forceinline__ u16 f2bf(float f) {
    union { float f; u32 i; } v; v.f = f;
    u32 r = v.i + 0x7FFFu + ((v.i >> 16) & 1u);
    return (u16)(r >> 16);
}

__device__ __forceinline__ short8 ld8(const u16* p) {
    return *(const short8*)p;
}

// v_permlane32_swap: a' = [a.lo, b.lo], b' = [a.hi, b.hi]
__device__ __forceinline__ void pl32swap(u32& a, u32& b) {
    asm("v_permlane32_swap_b32 %0, %1" : "+v"(a), "+v"(b));
}
__device__ __forceinline__ float xhalf_max(float x) {
    u32 a = __float_as_uint(x), b = a;
    pl32swap(a, b);
    return fmaxf(__uint_as_float(a), __uint_as_float(b));
}
__device__ __forceinline__ u32 cvtpk(float lo, float hi) {
    u32 r;
    asm("v_cvt_pk_bf16_f32 %0, %1, %2" : "=v"(r) : "v"(lo), "v"(hi));
    return r;
}
__device__ __forceinline__ float fexp2(float x) {
    float r;
    asm("v_exp_f32 %0, %1" : "=v"(r) : "v"(x));
    return r;
}
__device__ __forceinline__ float max3f(float a, float b, float c) {
    float r;
    asm("v_max3_f32 %0, %1, %2, %3" : "=v"(r) : "v"(a), "v"(b), "v"(c));
    return r;
}

#define QSCALE 0.18033610062f  /* 0.125 * log2(e) */
#define LOG2E  1.44269504089f

// ---------------- weight prep: transpose + bf16 cast + imp pack ----------------
__global__ __launch_bounds__(256) void prep_kernel(
        const float* __restrict__ Wq, const float* __restrict__ Wk,
        const float* __restrict__ Wv, const float* __restrict__ Wo,
        const float* __restrict__ W1, const float* __restrict__ W2,
        const float* __restrict__ imp,
        u16* __restrict__ WqkvT, u16* __restrict__ WoT,
        u16* __restrict__ W1T, u16* __restrict__ W2T,
        u32* __restrict__ impPk) {
    int e = blockIdx.x * 256 + threadIdx.x;
    if (e < 196608) {                    // 768*256
        int c = e >> 8, k = e & 255;
        int mat = c >> 8;                // 0=q,1=k,2=v
        int cc = c & 255;
        const float* W = (mat == 0) ? Wq : ((mat == 1) ? Wk : Wv);
        WqkvT[(size_t)c * 256 + k] = f2bf(W[k * 256 + cc]);
    } else if (e < 262144) {
        int i = e - 196608; int n = i >> 8, k = i & 255;
        WoT[n * 256 + k] = f2bf(Wo[k * 256 + n]);
    } else if (e < 393216) {
        int i = e - 262144; int n = i >> 8, k = i & 255;
        W1T[n * 256 + k] = f2bf(W1[k * 512 + n]);
    } else if (e < 524288) {
        int i = e - 393216; int n = i >> 9, k = i & 511;
        W2T[n * 512 + k] = f2bf(W2[k * 256 + n]);
    } else {
        int i = e - 524288;              // 0..16383 = B*N importance entries
        float ivs = imp[i] * LOG2E;
        u16 ih = f2bf(ivs);
        float rem = ivs - __uint_as_float(((u32)ih) << 16);
        u16 il = f2bf(rem);
        impPk[i] = ((u32)il << 16) | ih;
    }
}

// ---------------- LayerNorm ----------------
__global__ __launch_bounds__(256) void ln_kernel(const float* __restrict__ x,
        const float* __restrict__ w, const float* __restrict__ bia,
        u16* __restrict__ out) {
    int lane = threadIdx.x & 63;
    int row = blockIdx.x * 4 + (threadIdx.x >> 6);
    const float* xr = x + (size_t)row * Dd;
    float4 v = *(const float4*)(xr + lane * 4);
    float s = v.x + v.y + v.z + v.w;
    float s2 = v.x * v.x + v.y * v.y + v.z * v.z + v.w * v.w;
    #pragma unroll
    for (int off = 1; off < 64; off <<= 1) {
        s  += __shfl_xor(s, off);
        s2 += __shfl_xor(s2, off);
    }
    float mu = s * (1.0f / Dd);
    float var = s2 * (1.0f / Dd) - mu * mu;
    float rstd = rsqrtf(var + 1e-5f);
    float4 wv = *(const float4*)(w + lane * 4);
    float4 bv = *(const float4*)(bia + lane * 4);
    ushort4 ov;
    ov.x = f2bf((v.x - mu) * rstd * wv.x + bv.x);
    ov.y = f2bf((v.y - mu) * rstd * wv.y + bv.y);
    ov.z = f2bf((v.z - mu) * rstd * wv.z + bv.z);
    ov.w = f2bf((v.w - mu) * rstd * wv.w + bv.w);
    *(ushort4*)(out + (size_t)row * Dd + lane * 4) = ov;
}

// ---------------- GEMM: A[M,K] bf16 x BT[N,K] bf16 -> epilogue ----------------
template<int MODE, int KD, int BM>
__global__ __launch_bounds__(256) void gemm_bt(
        const u16* __restrict__ A, const u16* __restrict__ BT,
        const float* __restrict__ bias0, const float* __restrict__ bias1,
        const float* __restrict__ bias2,
        const float* __restrict__ resid, float* __restrict__ outf,
        u16* __restrict__ o0, u16* __restrict__ o1, u16* __restrict__ o2) {
    constexpr int AM = BM / 32;          // A-frags per wave (4 or 2)
    __shared__ u16 Asl[BM * 32];
    __shared__ u16 Bsl[128 * 32];
    int lane = threadIdx.x & 63;
    int wv = threadIdx.x >> 6;
    int wm = wv >> 1, wn = wv & 1;
    int m0 = blockIdx.y * BM, n0 = blockIdx.x * 128;
    f32x4 zz; zz[0] = 0.f; zz[1] = 0.f; zz[2] = 0.f; zz[3] = 0.f;
    f32x4 acc[AM][4];
    #pragma unroll
    for (int i = 0; i < AM; ++i)
        #pragma unroll
        for (int j = 0; j < 4; ++j) acc[i][j] = zz;

    for (int kt = 0; kt < KD; kt += 32) {
        __syncthreads();
        #pragma unroll
        for (int i = 0; i < BM / 64; ++i) {      // A: BM*4 16B-chunks
            int chunk = threadIdx.x + i * 256;
            int row = chunk >> 2, c16 = chunk & 3;
            int srcc = (c16 ^ (row & 3)) * 8;
            gload_lds16(A + (size_t)(m0 + row) * KD + kt + srcc,
                        (char*)Asl + wv * 1024 + i * 4096);
        }
        #pragma unroll
        for (int i = 0; i < 2; ++i) {            // B: 512 16B-chunks
            int chunk = threadIdx.x + i * 256;
            int row = chunk >> 2, c16 = chunk & 3;
            int srcc = (c16 ^ (row & 3)) * 8;
            gload_lds16(BT + (size_t)(n0 + row) * KD + kt + srcc,
                        (char*)Bsl + wv * 1024 + i * 4096);
        }
        __syncthreads();
        short8 af[AM], bfr[4];
        #pragma unroll
        for (int t = 0; t < AM; ++t) {
            int arow = wm * (BM / 2) + t * 16 + (lane & 15);
            af[t] = ld8(Asl + arow * 32 + (((lane >> 4) * 8) ^ ((arow & 3) * 8)));
        }
        #pragma unroll
        for (int t = 0; t < 4; ++t) {
            int brow = wn * 64 + t * 16 + (lane & 15);
            bfr[t] = ld8(Bsl + brow * 32 + (((lane >> 4) * 8) ^ ((brow & 3) * 8)));
        }
        #pragma unroll
        for (int mt = 0; mt < AM; ++mt)
            #pragma unroll
            for (int nt = 0; nt < 4; ++nt)
                acc[mt][nt] = __builtin_amdgcn_mfma_f32_16x16x32_bf16(af[mt], bfr[nt], acc[mt][nt], 0, 0, 0);
    }

    #pragma unroll
    for (int mt = 0; mt < AM; ++mt) {
        #pragma unroll
        for (int nt = 0; nt < 4; ++nt) {
            #pragma unroll
            for (int r = 0; r < 4; ++r) {
                int row = m0 + wm * (BM / 2) + mt * 16 + (lane >> 4) * 4 + r;
                int col = n0 + wn * 64 + nt * 16 + (lane & 15);
                float v = acc[mt][nt][r];
                if (MODE == 0) {
                    int mat = col >> 8;
                    int cc = col & 255;
                    int hh = cc >> 6, dd = cc & 63;
                    int bbi = row >> 12, nni = row & 4095;
                    int bh = bbi * Hh + hh;
                    // q pre-scaled by 0.125*log2(e) for exp2-domain flash attention
                    if (mat == 0)      o0[((size_t)bh * Nn + nni) * HDd + dd] = f2bf((v + bias0[cc]) * QSCALE);
                    else if (mat == 1) o1[((size_t)bh * Nn + nni) * HDd + dd] = f2bf(v + bias1[cc]);
                    else               o2[((size_t)bh * HDd + dd) * Nn + nni] = f2bf(v + bias2[cc]);
                } else if (MODE == 2) {
                    float xg = v + bias0[col];
                    float g = 0.5f * xg * (1.0f + erff(xg * 0.70710678118654752f));
                    o0[(size_t)row * FFf + col] = f2bf(g);
                } else {
                    outf[(size_t)row * Dd + col] = resid[(size_t)row * Dd + col] + v + bias0[col];
                }
            }
        }
    }
}

// ---------------- out-proj + residual + LayerNorm2 fused ----------------
__global__ __launch_bounds__(256) void oproj_ln_kernel(
        const u16* __restrict__ A, const u16* __restrict__ BT,
        const float* __restrict__ bias, const float* __restrict__ resid,
        const float* __restrict__ lnw, const float* __restrict__ lnb,
        float* __restrict__ x2, u16* __restrict__ yln) {
    __shared__ u16 Asl[32 * 32];
    __shared__ u16 Bsl[256 * 32];
    __shared__ float xlds[32][256];
    int lane = threadIdx.x & 63;
    int wv = threadIdx.x >> 6;
    int m0 = blockIdx.x * 32;
    f32x4 zz; zz[0] = 0.f; zz[1] = 0.f; zz[2] = 0.f; zz[3] = 0.f;
    f32x4 acc[2][4];
    #pragma unroll
    for (int i = 0; i < 2; ++i)
        #pragma unroll
        for (int j = 0; j < 4; ++j) acc[i][j] = zz;

    for (int kt = 0; kt < Dd; kt += 32) {
        __syncthreads();
        if (wv < 2) {                            // A: 128 16B-chunks
            int t = threadIdx.x;
            int row = t >> 2, c16 = t & 3;
            int srcc = (c16 ^ (row & 3)) * 8;
            gload_lds16(A + (size_t)(m0 + row) * Dd + kt + srcc,
                        (char*)Asl + wv * 1024);
        }
        #pragma unroll
        for (int i = 0; i < 4; ++i) {            // B: 1024 16B-chunks (all 256 rows)
            int chunk = threadIdx.x + i * 256;
            int row = chunk >> 2, c16 = chunk & 3;
            int srcc = (c16 ^ (row & 3)) * 8;
            gload_lds16(BT + (size_t)row * Dd + kt + srcc,
                        (char*)Bsl + wv * 1024 + i * 4096);
        }
        __syncthreads();
        short8 af[2], bfr[4];
        #pragma unroll
        for (int t = 0; t < 2; ++t) {
            int arow = t * 16 + (lane & 15);
            af[t] = ld8(Asl + arow * 32 + (((lane >> 4) * 8) ^ ((arow & 3) * 8)));
        }
        #pragma unroll
        for (int t = 0; t < 4; ++t) {
            int brow = wv * 64 + t * 16 + (lane & 15);
            bfr[t] = ld8(Bsl + brow * 32 + (((lane >> 4) * 8) ^ ((brow & 3) * 8)));
        }
        #pragma unroll
        for (int mt = 0; mt < 2; ++mt)
            #pragma unroll
            for (int nt = 0; nt < 4; ++nt)
                acc[mt][nt] = __builtin_amdgcn_mfma_f32_16x16x32_bf16(af[mt], bfr[nt], acc[mt][nt], 0, 0, 0);
    }

    // epilogue: x2 = resid + acc + bias -> global + LDS
    #pragma unroll
    for (int mt = 0; mt < 2; ++mt) {
        #pragma unroll
        for (int nt = 0; nt < 4; ++nt) {
            #pragma unroll
            for (int r = 0; r < 4; ++r) {
                int row = mt * 16 + (lane >> 4) * 4 + r;
                int col = wv * 64 + nt * 16 + (lane & 15);
                float v = resid[(size_t)(m0 + row) * Dd + col] + acc[mt][nt][r] + bias[col];
                x2[(size_t)(m0 + row) * Dd + col] = v;
                xlds[row][col] = v;
            }
        }
    }
    __syncthreads();

    // LN over full rows: 8 threads/row, 32 cols each
    int rw = threadIdx.x >> 3;
    int cg = (threadIdx.x & 7) * 32;
    float s = 0.f, s2 = 0.f;
    #pragma unroll
    for (int j = 0; j < 32; ++j) {
        float v = xlds[rw][cg + j];
        s += v; s2 += v * v;
    }
    #pragma unroll
    for (int off = 1; off < 8; off <<= 1) {
        s  += __shfl_xor(s, off);
        s2 += __shfl_xor(s2, off);
    }
    float mu = s * (1.0f / Dd);
    float var = s2 * (1.0f / Dd) - mu * mu;
    float rstd = rsqrtf(var + 1e-5f);
    u16* op = yln + (size_t)(m0 + rw) * Dd + cg;
    #pragma unroll
    for (int j = 0; j < 32; j += 8) {
        float v0 = (xlds[rw][cg + j + 0] - mu) * rstd * lnw[cg + j + 0] + lnb[cg + j + 0];
        float v1 = (xlds[rw][cg + j + 1] - mu) * rstd * lnw[cg + j + 1] + lnb[cg + j + 1];
        float v2 = (xlds[rw][cg + j + 2] - mu) * rstd * lnw[cg + j + 2] + lnb[cg + j + 2];
        float v3 = (xlds[rw][cg + j + 3] - mu) * rstd * lnw[cg + j + 3] + lnb[cg + j + 3];
        float v4 = (xlds[rw][cg + j + 4] - mu) * rstd * lnw[cg + j + 4] + lnb[cg + j + 4];
        float v5 = (xlds[rw][cg + j + 5] - mu) * rstd * lnw[cg + j + 5] + lnb[cg + j + 5];
        float v6 = (xlds[rw][cg + j + 6] - mu) * rstd * lnw[cg + j + 6] + lnb[cg + j + 6];
        float v7 = (xlds[rw][cg + j + 7] - mu) * rstd * lnw[cg + j + 7] + lnb[cg + j + 7];
        uint4 pk;
        pk.x = cvtpk(v0, v1); pk.y = cvtpk(v2, v3);
        pk.z = cvtpk(v4, v5); pk.w = cvtpk(v6, v7);
        *(uint4*)(op + j) = pk;
    }
}

// ---------------- Flash attention, KV-split x4, 2-qset waves ----------------
// grid: 4 quarters x 16 bh x 16 qt(256). 4 waves x 64 q-rows (two 32-q sets).
// 4 blocks/CU (VGPR<=128, LDS 32KB): TLP fills the ~38% issue-stall of the
// 2-qset body. Writes unnormalized ctx^T partials (bf16) + m,l per quarter.
__global__ __launch_bounds__(256, 4) void attn_kernel(
        const u16* __restrict__ Qb, const u16* __restrict__ Kb,
        const u16* __restrict__ VTb, const u32* __restrict__ impPk,
        u16* __restrict__ pc, float* __restrict__ pm, float* __restrict__ pl) {
    __shared__ u16 Klds[2][64 * 64];
    __shared__ u16 Vlds[2][64 * 64];
    int lane = threadIdx.x & 63;
    int wv = threadIdx.x >> 6;
    int kvq = blockIdx.x >> 8;           // 0..3
    int bh = (blockIdx.x >> 4) & 15;
    int qt = blockIdx.x & 15;
    int bbi = bh >> 2;
    int qrow0 = qt * 256 + wv * 64;
    int q = lane & 31;
    int hf = lane >> 5;
    int key0 = kvq * 1024;
    int pg = kvq * 16 + bh;

    // Q B-frags, two qsets
    short8 qfA[4], qfB[4];
    #pragma unroll
    for (int ks = 0; ks < 4; ++ks) {
        qfA[ks] = ld8(Qb + ((size_t)bh * Nn + qrow0 + q) * HDd + ks * 16 + hf * 8);
        qfB[ks] = ld8(Qb + ((size_t)bh * Nn + qrow0 + 32 + q) * HDd + ks * 16 + hf * 8);
    }

    // B-frag with ones at k=0,1 (importance augmentation)
    short8 onef = (short8)0;
    if (hf == 0) { onef[0] = (short)0x3F80; onef[1] = (short)0x3F80; }
    // row-split all-ones A-frags: aoneLo -> rows 0-15 (qsetA), aoneHi -> 16-31
    short8 aoneLo = (short8)0, aoneHi = (short8)0;
    if ((lane & 31) < 16) {
        #pragma unroll
        for (int j = 0; j < 8; ++j) aoneLo[j] = (short)0x3F80;
    } else {
        #pragma unroll
        for (int j = 0; j < 8; ++j) aoneHi[j] = (short)0x3F80;
    }

    // staging: lane covers LDS row base+(l>>3), slot l&7; source pre-swizzled
    int sr = lane >> 3;
    int sc = lane & 7;
    int swz = (sc ^ sr) * 8;
    const u16* kp = Kb + ((size_t)bh * Nn + key0 + wv * 16 + sr) * HDd + swz;
    const u16* vp = VTb + ((size_t)bh * HDd + wv * 16 + sr) * Nn + key0 + swz;
    size_t ib = (size_t)bbi * Nn;

    gload_lds16(kp,           (char*)Klds[0] + wv * 2048);
    gload_lds16(kp + 8 * HDd, (char*)Klds[0] + wv * 2048 + 1024);
    gload_lds16(vp,           (char*)Vlds[0] + wv * 2048);
    gload_lds16(vp + 8 * Nn,  (char*)Vlds[0] + wv * 2048 + 1024);
    kp += 64 * HDd; vp += 64;
    u32 npk0 = impPk[ib + key0 + q], npk1 = impPk[ib + key0 + 32 + q];

    f32x16 ctxA[2], ctxB[2], lacc;
    #pragma unroll
    for (int r = 0; r < 16; ++r) {
        ctxA[0][r] = 0.f; ctxA[1][r] = 0.f;
        ctxB[0][r] = 0.f; ctxB[1][r] = 0.f;
        lacc[r] = 0.f;
    }
    float mA = -__builtin_inff(), mB = -__builtin_inff();

    int cur = 0;
    for (int t = 0; t < 16; ++t) {
        __syncthreads();   // buf[cur] ready; buf[cur^1] free
        u32 pk0 = npk0, pk1 = npk1;
        if (t < 15) {
            gload_lds16(kp,           (char*)Klds[cur ^ 1] + wv * 2048);
            gload_lds16(kp + 8 * HDd, (char*)Klds[cur ^ 1] + wv * 2048 + 1024);
            gload_lds16(vp,           (char*)Vlds[cur ^ 1] + wv * 2048);
            gload_lds16(vp + 8 * Nn,  (char*)Vlds[cur ^ 1] + wv * 2048 + 1024);
            kp += 64 * HDd; vp += 64;
            npk0 = impPk[ib + key0 + t * 64 + 64 + q];
            npk1 = impPk[ib + key0 + t * 64 + 96 + q];
        }
        const u16* Kc = Klds[cur];
        const u16* Vc = Vlds[cur];

        // ---- QK^T: K-frags shared across both qsets ----
        f32x16 sA0, sA1, sB0, sB1;
        #pragma unroll
        for (int r = 0; r < 16; ++r) { sA0[r] = 0.f; sA1[r] = 0.f; sB0[r] = 0.f; sB1[r] = 0.f; }
        __builtin_amdgcn_s_setprio(1);
        #pragma unroll
        for (int ks = 0; ks < 4; ++ks) {
            short8 kf0 = ld8(Kc + q * 64 + (((ks * 2 + hf) ^ (q & 7)) * 8));
            short8 kf1 = ld8(Kc + (32 + q) * 64 + (((ks * 2 + hf) ^ (q & 7)) * 8));
            sA0 = __builtin_amdgcn_mfma_f32_32x32x16_bf16(kf0, qfA[ks], sA0, 0, 0, 0);
            sA1 = __builtin_amdgcn_mfma_f32_32x32x16_bf16(kf1, qfA[ks], sA1, 0, 0, 0);
            sB0 = __builtin_amdgcn_mfma_f32_32x32x16_bf16(kf0, qfB[ks], sB0, 0, 0, 0);
            sB1 = __builtin_amdgcn_mfma_f32_32x32x16_bf16(kf1, qfB[ks], sB1, 0, 0, 0);
        }
        short8 af0 = (short8)0, af1 = (short8)0;
        if (hf == 0) {
            af0[0] = (short)(pk0 & 0xFFFFu); af0[1] = (short)(pk0 >> 16);
            af1[0] = (short)(pk1 & 0xFFFFu); af1[1] = (short)(pk1 >> 16);
        }
        sA0 = __builtin_amdgcn_mfma_f32_32x32x16_bf16(af0, onef, sA0, 0, 0, 0);
        sA1 = __builtin_amdgcn_mfma_f32_32x32x16_bf16(af1, onef, sA1, 0, 0, 0);
        sB0 = __builtin_amdgcn_mfma_f32_32x32x16_bf16(af0, onef, sB0, 0, 0, 0);
        sB1 = __builtin_amdgcn_mfma_f32_32x32x16_bf16(af1, onef, sB1, 0, 0, 0);
        __builtin_amdgcn_s_setprio(0);

        // ---- softmax qsetA ----
        {
            float a0 = max3f(sA0[0], sA0[1], sA0[2]);
            float a1 = max3f(sA0[3], sA0[4], sA0[5]);
            float a2 = max3f(sA0[6], sA0[7], sA0[8]);
            float a3 = max3f(sA0[9], sA0[10], sA0[11]);
            float a4 = max3f(sA0[12], sA0[13], sA0[14]);
            float b0 = max3f(sA1[0], sA1[1], sA1[2]);
            float b1 = max3f(sA1[3], sA1[4], sA1[5]);
            float b2 = max3f(sA1[6], sA1[7], sA1[8]);
            float b3 = max3f(sA1[9], sA1[10], sA1[11]);
            float b4 = max3f(sA1[12], sA1[13], sA1[14]);
            float c0 = max3f(a0, a1, a2);
            float c1 = max3f(a3, a4, sA0[15]);
            float c2 = max3f(b0, b1, b2);
            float c3 = max3f(b3, b4, sA1[15]);
            float tm = xhalf_max(fmaxf(max3f(c0, c1, c2), c3));
            bool nore = __all(tm <= mA + 8.0f);
            if (!nore) {
                float nm = fmaxf(mA, tm);
                float al = fexp2(mA - nm);
                #pragma unroll
                for (int r = 0; r < 8; ++r) lacc[r] *= al;   // qsetA rows 0-15
                #pragma unroll
                for (int r = 0; r < 16; ++r) { ctxA[0][r] *= al; ctxA[1][r] *= al; }
                mA = nm;
            }
            #pragma unroll
            for (int r = 0; r < 16; ++r) { sA0[r] = fexp2(sA0[r] - mA); sA1[r] = fexp2(sA1[r] - mA); }
        }
        // ---- softmax qsetB ----
        {
            float a0 = max3f(sB0[0], sB0[1], sB0[2]);
            float a1 = max3f(sB0[3], sB0[4], sB0[5]);
            float a2 = max3f(sB0[6], sB0[7], sB0[8]);
            float a3 = max3f(sB0[9], sB0[10], sB0[11]);
            float a4 = max3f(sB0[12], sB0[13], sB0[14]);
            float b0 = max3f(sB1[0], sB1[1], sB1[2]);
            float b1 = max3f(sB1[3], sB1[4], sB1[5]);
            float b2 = max3f(sB1[6], sB1[7], sB1[8]);
            float b3 = max3f(sB1[9], sB1[10], sB1[11]);
            float b4 = max3f(sB1[12], sB1[13], sB1[14]);
            float c0 = max3f(a0, a1, a2);
            float c1 = max3f(a3, a4, sB0[15]);
            float c2 = max3f(b0, b1, b2);
            float c3 = max3f(b3, b4, sB1[15]);
            float tm = xhalf_max(fmaxf(max3f(c0, c1, c2), c3));
            bool nore = __all(tm <= mB + 8.0f);
            if (!nore) {
                float nm = fmaxf(mB, tm);
                float al = fexp2(mB - nm);
                #pragma unroll
                for (int r = 8; r < 16; ++r) lacc[r] *= al;  // qsetB rows 16-31
                #pragma unroll
                for (int r = 0; r < 16; ++r) { ctxB[0][r] *= al; ctxB[1][r] *= al; }
                mB = nm;
            }
            #pragma unroll
            for (int r = 0; r < 16; ++r) { sB0[r] = fexp2(sB0[r] - mB); sB1[r] = fexp2(sB1[r] - mB); }
        }

        // ---- P -> bf16 B-frags in-register (both qsets) ----
        u32 wA0[8], wA1[8], wB0[8], wB1[8];
        #pragma unroll
        for (int j = 0; j < 8; ++j) {
            wA0[j] = cvtpk(sA0[2 * j], sA0[2 * j + 1]);
            wA1[j] = cvtpk(sA1[2 * j], sA1[2 * j + 1]);
            wB0[j] = cvtpk(sB0[2 * j], sB0[2 * j + 1]);
            wB1[j] = cvtpk(sB1[2 * j], sB1[2 * j + 1]);
        }
        pl32swap(wA0[0], wA0[2]); pl32swap(wA0[1], wA0[3]);
        pl32swap(wA0[4], wA0[6]); pl32swap(wA0[5], wA0[7]);
        pl32swap(wA1[0], wA1[2]); pl32swap(wA1[1], wA1[3]);
        pl32swap(wA1[4], wA1[6]); pl32swap(wA1[5], wA1[7]);
        pl32swap(wB0[0], wB0[2]); pl32swap(wB0[1], wB0[3]);
        pl32swap(wB0[4], wB0[6]); pl32swap(wB0[5], wB0[7]);
        pl32swap(wB1[0], wB1[2]); pl32swap(wB1[1], wB1[3]);
        pl32swap(wB1[4], wB1[6]); pl32swap(wB1[5], wB1[7]);
        short8 pfA[4], pfB[4];
        {
            u32x4 t0; t0[0] = wA0[0]; t0[1] = wA0[1]; t0[2] = wA0[2]; t0[3] = wA0[3];
            u32x4 t1; t1[0] = wA0[4]; t1[1] = wA0[5]; t1[2] = wA0[6]; t1[3] = wA0[7];
            u32x4 t2; t2[0] = wA1[0]; t2[1] = wA1[1]; t2[2] = wA1[2]; t2[3] = wA1[3];
            u32x4 t3; t3[0] = wA1[4]; t3[1] = wA1[5]; t3[2] = wA1[6]; t3[3] = wA1[7];
            pfA[0] = __builtin_bit_cast(short8, t0);
            pfA[1] = __builtin_bit_cast(short8, t1);
            pfA[2] = __builtin_bit_cast(short8, t2);
            pfA[3] = __builtin_bit_cast(short8, t3);
            u32x4 u0; u0[0] = wB0[0]; u0[1] = wB0[1]; u0[2] = wB0[2]; u0[3] = wB0[3];
            u32x4 u1; u1[0] = wB0[4]; u1[1] = wB0[5]; u1[2] = wB0[6]; u1[3] = wB0[7];
            u32x4 u2; u2[0] = wB1[0]; u2[1] = wB1[1]; u2[2] = wB1[2]; u2[3] = wB1[3];
            u32x4 u3; u3[0] = wB1[4]; u3[1] = wB1[5]; u3[2] = wB1[6]; u3[3] = wB1[7];
            pfB[0] = __builtin_bit_cast(short8, u0);
            pfB[1] = __builtin_bit_cast(short8, u1);
            pfB[2] = __builtin_bit_cast(short8, u2);
            pfB[3] = __builtin_bit_cast(short8, u3);
        }

        // ---- PV + l-accumulation: V-frags shared across qsets ----
        __builtin_amdgcn_s_setprio(1);
        #pragma unroll
        for (int j = 0; j < 4; ++j) {
            lacc = __builtin_amdgcn_mfma_f32_32x32x16_bf16(aoneLo, pfA[j], lacc, 0, 0, 0);
            lacc = __builtin_amdgcn_mfma_f32_32x32x16_bf16(aoneHi, pfB[j], lacc, 0, 0, 0);
        }
        #pragma unroll
        for (int dt = 0; dt < 2; ++dt) {
            int vrow = dt * 32 + q;
            const u16* vb = Vc + vrow * 64;
            int sw = vrow & 7;
            #pragma unroll
            for (int j = 0; j < 4; ++j) {
                short8 vf = ld8(vb + (((2 * j + hf) ^ sw) * 8));
                ctxA[dt] = __builtin_amdgcn_mfma_f32_32x32x16_bf16(vf, pfA[j], ctxA[dt], 0, 0, 0);
                ctxB[dt] = __builtin_amdgcn_mfma_f32_32x32x16_bf16(vf, pfB[j], ctxB[dt], 0, 0, 0);
            }
        }
        __builtin_amdgcn_s_setprio(0);
        cur ^= 1;
    }

    // ---- epilogue: write unnormalized partials (both qsets) ----
    int qgA = qrow0 + q, qgB = qrow0 + 32 + q;
    if (hf == 0) {
        pm[(size_t)pg * Nn + qgA] = mA;
        pl[(size_t)pg * Nn + qgA] = lacc[0];   // qsetA rows 0-15
        pm[(size_t)pg * Nn + qgB] = mB;
        pl[(size_t)pg * Nn + qgB] = lacc[8];   // qsetB rows 16-31
    }
    #pragma unroll
    for (int dt = 0; dt < 2; ++dt) {
        #pragma unroll
        for (int r = 0; r < 16; ++r) {
            int d = dt * 32 + (r & 3) + 8 * (r >> 2) + 4 * hf;
            pc[((size_t)pg * 64 + d) * Nn + qgA] = f2bf(ctxA[dt][r]);
            pc[((size_t)pg * 64 + d) * Nn + qgB] = f2bf(ctxB[dt][r]);
        }
    }
}

// ---------------- merge: combine 4 KV-quarters, transpose to ctx layout ----------------
__global__ __launch_bounds__(256) void merge_kernel(
        const u16* __restrict__ pc, const float* __restrict__ pm,
        const float* __restrict__ pl, u16* __restrict__ ctxOut) {
    __shared__ float trans[64][65];
    __shared__ float fw[4][64];
    int bh = blockIdx.x >> 6;
    int q0 = (blockIdx.x & 63) * 64;
    int t = threadIdx.x;
    if (t < 64) {
        int qg = q0 + t;
        float m0 = pm[(size_t)(bh) * Nn + qg];
        float m1 = pm[(size_t)(16 + bh) * Nn + qg];
        float m2 = pm[(size_t)(32 + bh) * Nn + qg];
        float m3 = pm[(size_t)(48 + bh) * Nn + qg];
        float M = fmaxf(fmaxf(m0, m1), fmaxf(m2, m3));
        float w0 = fexp2(m0 - M), w1 = fexp2(m1 - M);
        float w2 = fexp2(m2 - M), w3 = fexp2(m3 - M);
        float l = pl[(size_t)(bh) * Nn + qg] * w0
                + pl[(size_t)(16 + bh) * Nn + qg] * w1
                + pl[(size_t)(32 + bh) * Nn + qg] * w2
                + pl[(size_t)(48 + bh) * Nn + qg] * w3;
        float inv = 1.0f / l;
        fw[0][t] = w0 * inv; fw[1][t] = w1 * inv;
        fw[2][t] = w2 * inv; fw[3][t] = w3 * inv;
    }
    __syncthreads();
    int wv = t >> 6, lane = t & 63;
    #pragma unroll
    for (int i = 0; i < 16; ++i) {
        int d = wv * 16 + i;
        float acc = 0.f;
        #pragma unroll
        for (int j = 0; j < 4; ++j) {
            float c = __uint_as_float((u32)pc[((size_t)(j * 16 + bh) * 64 + d) * Nn + q0 + lane] << 16);
            acc += c * fw[j][lane];
        }
        trans[lane][d] = acc;
    }
    __syncthreads();
    int q = t >> 2, dg = t & 3;
    int b = bh >> 2, h = bh & 3;
    const float* tr = &trans[q][dg * 16];
    uint4 pa, pb;
    pa.x = cvtpk(tr[0], tr[1]);  pa.y = cvtpk(tr[2], tr[3]);
    pa.z = cvtpk(tr[4], tr[5]);  pa.w = cvtpk(tr[6], tr[7]);
    pb.x = cvtpk(tr[8], tr[9]);  pb.y = cvtpk(tr[10], tr[11]);
    pb.z = cvtpk(tr[12], tr[13]); pb.w = cvtpk(tr[14], tr[15]);
    u16* op = ctxOut + ((size_t)b * Nn + q0 + q) * Dd + h * 64 + dg * 16;
    *(uint4*)op = pa;
    *(uint4*)(op + 8) = pb;
}

extern "C" void kernel_launch(void* const* d_in, const int* in_sizes, int n_in,
                              void* d_out, int out_size, void* d_ws, size_t ws_size,
                              hipStream_t stream) {
    (void)in_sizes; (void)n_in; (void)out_size; (void)ws_size;
    const float* tokens     = (const float*)d_in[0];
    const float* importance = (const float*)d_in[1];
    const float* n1w = (const float*)d_in[2];
    const float* n1b = (const float*)d_in[3];
    const float* Wq  = (const float*)d_in[4];
    const float* bq  = (const float*)d_in[5];
    const float* Wk  = (const float*)d_in[6];
    const float* bk  = (const float*)d_in[7];
    const float* Wv  = (const float*)d_in[8];
    const float* bv  = (const float*)d_in[9];
    const float* Wo  = (const float*)d_in[10];
    const float* bo  = (const float*)d_in[11];
    const float* n2w = (const float*)d_in[12];
    const float* n2b = (const float*)d_in[13];
    const float* W1  = (const float*)d_in[14];
    const float* b1  = (const float*)d_in[15];
    const float* W2  = (const float*)d_in[16];
    const float* b2  = (const float*)d_in[17];
    float* out = (float*)d_out;

    char* ws = (char*)d_ws;
    const size_t MB = (size_t)1 << 20;
    // Sequential reuse (single stream): yln reuses xln (dead after QKV GEMM);
    // hbuf reuses qb+kb (dead after attn); x2 = d_out (dead until out-proj).
    u16* xln   = (u16*)(ws);                    // 0..8MB   (later: yln)
    u16* qb    = (u16*)(ws + 8 * MB);           // 8..16MB  (later: hbuf lo)
    u16* kb    = (u16*)(ws + 16 * MB);          // 16..24MB (later: hbuf hi)
    u16* vT    = (u16*)(ws + 24 * MB);          // 24..32MB
    u16* ctx   = (u16*)(ws + 32 * MB);          // 32..40MB
    u16* pc    = (u16*)(ws + 40 * MB);          // 40..72MB [kvq*16+bh][64 d][4096 q]
    float* pm  = (float*)(ws + 72 * MB);        // 1MB
    float* pl  = (float*)(ws + 73 * MB);        // 1MB
    u16* WqkvT = (u16*)(ws + 74 * MB);          // 384KB
    u16* WoT   = (u16*)(ws + 74 * MB + 393216);
    u16* W1T   = (u16*)(ws + 74 * MB + 393216 + 131072);
    u16* W2T   = (u16*)(ws + 74 * MB + 393216 + 131072 + 262144);
    u32* impPk = (u32*)(ws + 74 * MB + 393216 + 131072 + 262144 + 262144);
    u16* yln   = xln;                           // reuse (xln dead after QKV)
    u16* hbuf  = qb;                            // reuse 16MB (qb+kb dead after attn)
    float* x2  = out;                           // reuse d_out as x2 scratch

    prep_kernel<<<2112, 256, 0, stream>>>(Wq, Wk, Wv, Wo, W1, W2, importance,
                                          WqkvT, WoT, W1T, W2T, impPk);
    ln_kernel<<<4096, 256, 0, stream>>>(tokens, n1w, n1b, xln);
    gemm_bt<0, 256, 128><<<dim3(6, 128), 256, 0, stream>>>(xln, WqkvT, bq, bk, bv,
                                                           nullptr, nullptr, qb, kb, vT);
    attn_kernel<<<1024, 256, 0, stream>>>(qb, kb, vT, impPk, pc, pm, pl);
    merge_kernel<<<1024, 256, 0, stream>>>(pc, pm, pl, ctx);
    oproj_ln_kernel<<<512, 256, 0, stream>>>(ctx, WoT, bo, tokens, n2w, n2b, x2, yln);
    gemm_bt<2, 256, 64><<<dim3(4, 256), 256, 0, stream>>>(yln, W1T, b1, nullptr, nullptr,
                                                          nullptr, nullptr, hbuf, nullptr, nullptr);
    gemm_bt<3, 512, 64><<<dim3(2, 256), 256, 0, stream>>>(hbuf, W2T, b2, nullptr, nullptr,
                                                          x2, out, nullptr, nullptr, nullptr);
}

// Round 15
// 193.270 us; speedup vs baseline: 3.2620x; 3.2620x over previous
//
#include <hip/hip_runtime.h>

#define Bb 4
#define Nn 4096
#define Dd 256
#define Hh 4
#define HDd 64
#define FFf 512
#define MT 16384  // B*N

typedef __attribute__((ext_vector_type(8))) short short8;
typedef __attribute__((ext_vector_type(4))) float f32x4;
typedef __attribute__((ext_vector_type(16))) float f32x16;
typedef unsigned short u16;
typedef unsigned int u32;
typedef __attribute__((ext_vector_type(4))) u32 u32x4;

typedef __attribute__((address_space(1))) const void glb_src;
typedef __attribute__((address_space(3))) void lds_dst;

__device__ __forceinline__ void gload_lds16(const void* g, void* l) {
    __builtin_amdgcn_global_load_lds((glb_src*)g, (lds_dst*)l, 16, 0, 0);
}

__device__ __forceinline__ u16 f2bf(float f) {
    union { float f; u32 i; } v; v.f = f;
    u32 r = v.i + 0x7FFFu + ((v.i >> 16) & 1u);
    return (u16)(r >> 16);
}

__device__ __forceinline__ short8 ld8(const u16* p) {
    return *(const short8*)p;
}

// v_permlane32_swap: a' = [a.lo, b.lo], b' = [a.hi, b.hi]
__device__ __forceinline__ void pl32swap(u32& a, u32& b) {
    asm("v_permlane32_swap_b32 %0, %1" : "+v"(a), "+v"(b));
}
__device__ __forceinline__ float xhalf_max(float x) {
    u32 a = __float_as_uint(x), b = a;
    pl32swap(a, b);
    return fmaxf(__uint_as_float(a), __uint_as_float(b));
}
__device__ __forceinline__ u32 cvtpk(float lo, float hi) {
    u32 r;
    asm("v_cvt_pk_bf16_f32 %0, %1, %2" : "=v"(r) : "v"(lo), "v"(hi));
    return r;
}
__device__ __forceinline__ float fexp2(float x) {
    float r;
    asm("v_exp_f32 %0, %1" : "=v"(r) : "v"(x));
    return r;
}
__device__ __forceinline__ float max3f(float a, float b, float c) {
    float r;
    asm("v_max3_f32 %0, %1, %2, %3" : "=v"(r) : "v"(a), "v"(b), "v"(c));
    return r;
}

#define QSCALE 0.18033610062f  /* 0.125 * log2(e) */
#define LOG2E  1.44269504089f

// ---------------- weight prep: transpose + bf16 cast + imp pack ----------------
__global__ __launch_bounds__(256) void prep_kernel(
        const float* __restrict__ Wq, const float* __restrict__ Wk,
        const float* __restrict__ Wv, const float* __restrict__ Wo,
        const float* __restrict__ W1, const float* __restrict__ W2,
        const float* __restrict__ imp,
        u16* __restrict__ WqkvT, u16* __restrict__ WoT,
        u16* __restrict__ W1T, u16* __restrict__ W2T,
        u32* __restrict__ impPk) {
    int e = blockIdx.x * 256 + threadIdx.x;
    if (e < 196608) {                    // 768*256
        int c = e >> 8, k = e & 255;
        int mat = c >> 8;                // 0=q,1=k,2=v
        int cc = c & 255;
        const float* W = (mat == 0) ? Wq : ((mat == 1) ? Wk : Wv);
        WqkvT[(size_t)c * 256 + k] = f2bf(W[k * 256 + cc]);
    } else if (e < 262144) {
        int i = e - 196608; int n = i >> 8, k = i & 255;
        WoT[n * 256 + k] = f2bf(Wo[k * 256 + n]);
    } else if (e < 393216) {
        int i = e - 262144; int n = i >> 8, k = i & 255;
        W1T[n * 256 + k] = f2bf(W1[k * 512 + n]);
    } else if (e < 524288) {
        int i = e - 393216; int n = i >> 9, k = i & 511;
        W2T[n * 512 + k] = f2bf(W2[k * 256 + n]);
    } else {
        int i = e - 524288;              // 0..16383 = B*N importance entries
        float ivs = imp[i] * LOG2E;
        u16 ih = f2bf(ivs);
        float rem = ivs - __uint_as_float(((u32)ih) << 16);
        u16 il = f2bf(rem);
        impPk[i] = ((u32)il << 16) | ih;
    }
}

// ---------------- LayerNorm ----------------
__global__ __launch_bounds__(256) void ln_kernel(const float* __restrict__ x,
        const float* __restrict__ w, const float* __restrict__ bia,
        u16* __restrict__ out) {
    int lane = threadIdx.x & 63;
    int row = blockIdx.x * 4 + (threadIdx.x >> 6);
    const float* xr = x + (size_t)row * Dd;
    float4 v = *(const float4*)(xr + lane * 4);
    float s = v.x + v.y + v.z + v.w;
    float s2 = v.x * v.x + v.y * v.y + v.z * v.z + v.w * v.w;
    #pragma unroll
    for (int off = 1; off < 64; off <<= 1) {
        s  += __shfl_xor(s, off);
        s2 += __shfl_xor(s2, off);
    }
    float mu = s * (1.0f / Dd);
    float var = s2 * (1.0f / Dd) - mu * mu;
    float rstd = rsqrtf(var + 1e-5f);
    float4 wv = *(const float4*)(w + lane * 4);
    float4 bv = *(const float4*)(bia + lane * 4);
    ushort4 ov;
    ov.x = f2bf((v.x - mu) * rstd * wv.x + bv.x);
    ov.y = f2bf((v.y - mu) * rstd * wv.y + bv.y);
    ov.z = f2bf((v.z - mu) * rstd * wv.z + bv.z);
    ov.w = f2bf((v.w - mu) * rstd * wv.w + bv.w);
    *(ushort4*)(out + (size_t)row * Dd + lane * 4) = ov;
}

// ---------------- GEMM: A[M,K] bf16 x BT[N,K] bf16 -> epilogue ----------------
template<int MODE, int KD, int BM>
__global__ __launch_bounds__(256) void gemm_bt(
        const u16* __restrict__ A, const u16* __restrict__ BT,
        const float* __restrict__ bias0, const float* __restrict__ bias1,
        const float* __restrict__ bias2,
        const float* __restrict__ resid, float* __restrict__ outf,
        u16* __restrict__ o0, u16* __restrict__ o1, u16* __restrict__ o2) {
    constexpr int AM = BM / 32;          // A-frags per wave (4 or 2)
    __shared__ u16 Asl[BM * 32];
    __shared__ u16 Bsl[128 * 32];
    int lane = threadIdx.x & 63;
    int wv = threadIdx.x >> 6;
    int wm = wv >> 1, wn = wv & 1;
    int m0 = blockIdx.y * BM, n0 = blockIdx.x * 128;
    f32x4 zz; zz[0] = 0.f; zz[1] = 0.f; zz[2] = 0.f; zz[3] = 0.f;
    f32x4 acc[AM][4];
    #pragma unroll
    for (int i = 0; i < AM; ++i)
        #pragma unroll
        for (int j = 0; j < 4; ++j) acc[i][j] = zz;

    for (int kt = 0; kt < KD; kt += 32) {
        __syncthreads();
        #pragma unroll
        for (int i = 0; i < BM / 64; ++i) {      // A: BM*4 16B-chunks
            int chunk = threadIdx.x + i * 256;
            int row = chunk >> 2, c16 = chunk & 3;
            int srcc = (c16 ^ (row & 3)) * 8;
            gload_lds16(A + (size_t)(m0 + row) * KD + kt + srcc,
                        (char*)Asl + wv * 1024 + i * 4096);
        }
        #pragma unroll
        for (int i = 0; i < 2; ++i) {            // B: 512 16B-chunks
            int chunk = threadIdx.x + i * 256;
            int row = chunk >> 2, c16 = chunk & 3;
            int srcc = (c16 ^ (row & 3)) * 8;
            gload_lds16(BT + (size_t)(n0 + row) * KD + kt + srcc,
                        (char*)Bsl + wv * 1024 + i * 4096);
        }
        __syncthreads();
        short8 af[AM], bfr[4];
        #pragma unroll
        for (int t = 0; t < AM; ++t) {
            int arow = wm * (BM / 2) + t * 16 + (lane & 15);
            af[t] = ld8(Asl + arow * 32 + (((lane >> 4) * 8) ^ ((arow & 3) * 8)));
        }
        #pragma unroll
        for (int t = 0; t < 4; ++t) {
            int brow = wn * 64 + t * 16 + (lane & 15);
            bfr[t] = ld8(Bsl + brow * 32 + (((lane >> 4) * 8) ^ ((brow & 3) * 8)));
        }
        #pragma unroll
        for (int mt = 0; mt < AM; ++mt)
            #pragma unroll
            for (int nt = 0; nt < 4; ++nt)
                acc[mt][nt] = __builtin_amdgcn_mfma_f32_16x16x32_bf16(af[mt], bfr[nt], acc[mt][nt], 0, 0, 0);
    }

    #pragma unroll
    for (int mt = 0; mt < AM; ++mt) {
        #pragma unroll
        for (int nt = 0; nt < 4; ++nt) {
            #pragma unroll
            for (int r = 0; r < 4; ++r) {
                int row = m0 + wm * (BM / 2) + mt * 16 + (lane >> 4) * 4 + r;
                int col = n0 + wn * 64 + nt * 16 + (lane & 15);
                float v = acc[mt][nt][r];
                if (MODE == 0) {
                    int mat = col >> 8;
                    int cc = col & 255;
                    int hh = cc >> 6, dd = cc & 63;
                    int bbi = row >> 12, nni = row & 4095;
                    int bh = bbi * Hh + hh;
                    // q pre-scaled by 0.125*log2(e) for exp2-domain flash attention
                    if (mat == 0)      o0[((size_t)bh * Nn + nni) * HDd + dd] = f2bf((v + bias0[cc]) * QSCALE);
                    else if (mat == 1) o1[((size_t)bh * Nn + nni) * HDd + dd] = f2bf(v + bias1[cc]);
                    else               o2[((size_t)bh * HDd + dd) * Nn + nni] = f2bf(v + bias2[cc]);
                } else if (MODE == 2) {
                    float xg = v + bias0[col];
                    float g = 0.5f * xg * (1.0f + erff(xg * 0.70710678118654752f));
                    o0[(size_t)row * FFf + col] = f2bf(g);
                } else {
                    outf[(size_t)row * Dd + col] = resid[(size_t)row * Dd + col] + v + bias0[col];
                }
            }
        }
    }
}

// ---------------- out-proj + residual + LayerNorm2 fused ----------------
__global__ __launch_bounds__(256) void oproj_ln_kernel(
        const u16* __restrict__ A, const u16* __restrict__ BT,
        const float* __restrict__ bias, const float* __restrict__ resid,
        const float* __restrict__ lnw, const float* __restrict__ lnb,
        float* __restrict__ x2, u16* __restrict__ yln) {
    __shared__ u16 Asl[32 * 32];
    __shared__ u16 Bsl[256 * 32];
    __shared__ float xlds[32][256];
    int lane = threadIdx.x & 63;
    int wv = threadIdx.x >> 6;
    int m0 = blockIdx.x * 32;
    f32x4 zz; zz[0] = 0.f; zz[1] = 0.f; zz[2] = 0.f; zz[3] = 0.f;
    f32x4 acc[2][4];
    #pragma unroll
    for (int i = 0; i < 2; ++i)
        #pragma unroll
        for (int j = 0; j < 4; ++j) acc[i][j] = zz;

    for (int kt = 0; kt < Dd; kt += 32) {
        __syncthreads();
        if (wv < 2) {                            // A: 128 16B-chunks
            int t = threadIdx.x;
            int row = t >> 2, c16 = t & 3;
            int srcc = (c16 ^ (row & 3)) * 8;
            gload_lds16(A + (size_t)(m0 + row) * Dd + kt + srcc,
                        (char*)Asl + wv * 1024);
        }
        #pragma unroll
        for (int i = 0; i < 4; ++i) {            // B: 1024 16B-chunks (all 256 rows)
            int chunk = threadIdx.x + i * 256;
            int row = chunk >> 2, c16 = chunk & 3;
            int srcc = (c16 ^ (row & 3)) * 8;
            gload_lds16(BT + (size_t)row * Dd + kt + srcc,
                        (char*)Bsl + wv * 1024 + i * 4096);
        }
        __syncthreads();
        short8 af[2], bfr[4];
        #pragma unroll
        for (int t = 0; t < 2; ++t) {
            int arow = t * 16 + (lane & 15);
            af[t] = ld8(Asl + arow * 32 + (((lane >> 4) * 8) ^ ((arow & 3) * 8)));
        }
        #pragma unroll
        for (int t = 0; t < 4; ++t) {
            int brow = wv * 64 + t * 16 + (lane & 15);
            bfr[t] = ld8(Bsl + brow * 32 + (((lane >> 4) * 8) ^ ((brow & 3) * 8)));
        }
        #pragma unroll
        for (int mt = 0; mt < 2; ++mt)
            #pragma unroll
            for (int nt = 0; nt < 4; ++nt)
                acc[mt][nt] = __builtin_amdgcn_mfma_f32_16x16x32_bf16(af[mt], bfr[nt], acc[mt][nt], 0, 0, 0);
    }

    // epilogue: x2 = resid + acc + bias -> global + LDS
    #pragma unroll
    for (int mt = 0; mt < 2; ++mt) {
        #pragma unroll
        for (int nt = 0; nt < 4; ++nt) {
            #pragma unroll
            for (int r = 0; r < 4; ++r) {
                int row = mt * 16 + (lane >> 4) * 4 + r;
                int col = wv * 64 + nt * 16 + (lane & 15);
                float v = resid[(size_t)(m0 + row) * Dd + col] + acc[mt][nt][r] + bias[col];
                x2[(size_t)(m0 + row) * Dd + col] = v;
                xlds[row][col] = v;
            }
        }
    }
    __syncthreads();

    // LN over full rows: 8 threads/row, 32 cols each
    int rw = threadIdx.x >> 3;
    int cg = (threadIdx.x & 7) * 32;
    float s = 0.f, s2 = 0.f;
    #pragma unroll
    for (int j = 0; j < 32; ++j) {
        float v = xlds[rw][cg + j];
        s += v; s2 += v * v;
    }
    #pragma unroll
    for (int off = 1; off < 8; off <<= 1) {
        s  += __shfl_xor(s, off);
        s2 += __shfl_xor(s2, off);
    }
    float mu = s * (1.0f / Dd);
    float var = s2 * (1.0f / Dd) - mu * mu;
    float rstd = rsqrtf(var + 1e-5f);
    u16* op = yln + (size_t)(m0 + rw) * Dd + cg;
    #pragma unroll
    for (int j = 0; j < 32; j += 8) {
        float v0 = (xlds[rw][cg + j + 0] - mu) * rstd * lnw[cg + j + 0] + lnb[cg + j + 0];
        float v1 = (xlds[rw][cg + j + 1] - mu) * rstd * lnw[cg + j + 1] + lnb[cg + j + 1];
        float v2 = (xlds[rw][cg + j + 2] - mu) * rstd * lnw[cg + j + 2] + lnb[cg + j + 2];
        float v3 = (xlds[rw][cg + j + 3] - mu) * rstd * lnw[cg + j + 3] + lnb[cg + j + 3];
        float v4 = (xlds[rw][cg + j + 4] - mu) * rstd * lnw[cg + j + 4] + lnb[cg + j + 4];
        float v5 = (xlds[rw][cg + j + 5] - mu) * rstd * lnw[cg + j + 5] + lnb[cg + j + 5];
        float v6 = (xlds[rw][cg + j + 6] - mu) * rstd * lnw[cg + j + 6] + lnb[cg + j + 6];
        float v7 = (xlds[rw][cg + j + 7] - mu) * rstd * lnw[cg + j + 7] + lnb[cg + j + 7];
        uint4 pk;
        pk.x = cvtpk(v0, v1); pk.y = cvtpk(v2, v3);
        pk.z = cvtpk(v4, v5); pk.w = cvtpk(v6, v7);
        *(uint4*)(op + j) = pk;
    }
}

// ---------------- Flash attention, KV-split x4, 2-qset waves ----------------
// grid: 4 quarters x 16 bh x 16 qt(256). 4 waves x 64 q-rows (two 32-q sets).
// launch_bounds(256,2): body needs ~116 VGPR; at 116 the HW fits 4 waves/SIMD
// naturally (floor(512/116)=4) -> 1024-block grid gives ~4 blocks/CU with NO
// forced VGPR cap (R14 lesson: (256,4) caps at 64 -> 2.5GB spill traffic).
__global__ __launch_bounds__(256, 2) void attn_kernel(
        const u16* __restrict__ Qb, const u16* __restrict__ Kb,
        const u16* __restrict__ VTb, const u32* __restrict__ impPk,
        u16* __restrict__ pc, float* __restrict__ pm, float* __restrict__ pl) {
    __shared__ u16 Klds[2][64 * 64];
    __shared__ u16 Vlds[2][64 * 64];
    int lane = threadIdx.x & 63;
    int wv = threadIdx.x >> 6;
    int kvq = blockIdx.x >> 8;           // 0..3
    int bh = (blockIdx.x >> 4) & 15;
    int qt = blockIdx.x & 15;
    int bbi = bh >> 2;
    int qrow0 = qt * 256 + wv * 64;
    int q = lane & 31;
    int hf = lane >> 5;
    int key0 = kvq * 1024;
    int pg = kvq * 16 + bh;

    // Q B-frags, two qsets
    short8 qfA[4], qfB[4];
    #pragma unroll
    for (int ks = 0; ks < 4; ++ks) {
        qfA[ks] = ld8(Qb + ((size_t)bh * Nn + qrow0 + q) * HDd + ks * 16 + hf * 8);
        qfB[ks] = ld8(Qb + ((size_t)bh * Nn + qrow0 + 32 + q) * HDd + ks * 16 + hf * 8);
    }

    // B-frag with ones at k=0,1 (importance augmentation)
    short8 onef = (short8)0;
    if (hf == 0) { onef[0] = (short)0x3F80; onef[1] = (short)0x3F80; }
    // row-split all-ones A-frags: aoneLo -> rows 0-15 (qsetA), aoneHi -> 16-31
    short8 aoneLo = (short8)0, aoneHi = (short8)0;
    if ((lane & 31) < 16) {
        #pragma unroll
        for (int j = 0; j < 8; ++j) aoneLo[j] = (short)0x3F80;
    } else {
        #pragma unroll
        for (int j = 0; j < 8; ++j) aoneHi[j] = (short)0x3F80;
    }

    // staging: lane covers LDS row base+(l>>3), slot l&7; source pre-swizzled
    int sr = lane >> 3;
    int sc = lane & 7;
    int swz = (sc ^ sr) * 8;
    const u16* kp = Kb + ((size_t)bh * Nn + key0 + wv * 16 + sr) * HDd + swz;
    const u16* vp = VTb + ((size_t)bh * HDd + wv * 16 + sr) * Nn + key0 + swz;
    size_t ib = (size_t)bbi * Nn;

    gload_lds16(kp,           (char*)Klds[0] + wv * 2048);
    gload_lds16(kp + 8 * HDd, (char*)Klds[0] + wv * 2048 + 1024);
    gload_lds16(vp,           (char*)Vlds[0] + wv * 2048);
    gload_lds16(vp + 8 * Nn,  (char*)Vlds[0] + wv * 2048 + 1024);
    kp += 64 * HDd; vp += 64;
    u32 npk0 = impPk[ib + key0 + q], npk1 = impPk[ib + key0 + 32 + q];

    f32x16 ctxA[2], ctxB[2], lacc;
    #pragma unroll
    for (int r = 0; r < 16; ++r) {
        ctxA[0][r] = 0.f; ctxA[1][r] = 0.f;
        ctxB[0][r] = 0.f; ctxB[1][r] = 0.f;
        lacc[r] = 0.f;
    }
    float mA = -__builtin_inff(), mB = -__builtin_inff();

    int cur = 0;
    for (int t = 0; t < 16; ++t) {
        __syncthreads();   // buf[cur] ready; buf[cur^1] free
        u32 pk0 = npk0, pk1 = npk1;
        if (t < 15) {
            gload_lds16(kp,           (char*)Klds[cur ^ 1] + wv * 2048);
            gload_lds16(kp + 8 * HDd, (char*)Klds[cur ^ 1] + wv * 2048 + 1024);
            gload_lds16(vp,           (char*)Vlds[cur ^ 1] + wv * 2048);
            gload_lds16(vp + 8 * Nn,  (char*)Vlds[cur ^ 1] + wv * 2048 + 1024);
            kp += 64 * HDd; vp += 64;
            npk0 = impPk[ib + key0 + t * 64 + 64 + q];
            npk1 = impPk[ib + key0 + t * 64 + 96 + q];
        }
        const u16* Kc = Klds[cur];
        const u16* Vc = Vlds[cur];

        // ---- QK^T: K-frags shared across both qsets ----
        f32x16 sA0, sA1, sB0, sB1;
        #pragma unroll
        for (int r = 0; r < 16; ++r) { sA0[r] = 0.f; sA1[r] = 0.f; sB0[r] = 0.f; sB1[r] = 0.f; }
        __builtin_amdgcn_s_setprio(1);
        #pragma unroll
        for (int ks = 0; ks < 4; ++ks) {
            short8 kf0 = ld8(Kc + q * 64 + (((ks * 2 + hf) ^ (q & 7)) * 8));
            short8 kf1 = ld8(Kc + (32 + q) * 64 + (((ks * 2 + hf) ^ (q & 7)) * 8));
            sA0 = __builtin_amdgcn_mfma_f32_32x32x16_bf16(kf0, qfA[ks], sA0, 0, 0, 0);
            sA1 = __builtin_amdgcn_mfma_f32_32x32x16_bf16(kf1, qfA[ks], sA1, 0, 0, 0);
            sB0 = __builtin_amdgcn_mfma_f32_32x32x16_bf16(kf0, qfB[ks], sB0, 0, 0, 0);
            sB1 = __builtin_amdgcn_mfma_f32_32x32x16_bf16(kf1, qfB[ks], sB1, 0, 0, 0);
        }
        short8 af0 = (short8)0, af1 = (short8)0;
        if (hf == 0) {
            af0[0] = (short)(pk0 & 0xFFFFu); af0[1] = (short)(pk0 >> 16);
            af1[0] = (short)(pk1 & 0xFFFFu); af1[1] = (short)(pk1 >> 16);
        }
        sA0 = __builtin_amdgcn_mfma_f32_32x32x16_bf16(af0, onef, sA0, 0, 0, 0);
        sA1 = __builtin_amdgcn_mfma_f32_32x32x16_bf16(af1, onef, sA1, 0, 0, 0);
        sB0 = __builtin_amdgcn_mfma_f32_32x32x16_bf16(af0, onef, sB0, 0, 0, 0);
        sB1 = __builtin_amdgcn_mfma_f32_32x32x16_bf16(af1, onef, sB1, 0, 0, 0);
        __builtin_amdgcn_s_setprio(0);

        // ---- softmax qsetA ----
        {
            float a0 = max3f(sA0[0], sA0[1], sA0[2]);
            float a1 = max3f(sA0[3], sA0[4], sA0[5]);
            float a2 = max3f(sA0[6], sA0[7], sA0[8]);
            float a3 = max3f(sA0[9], sA0[10], sA0[11]);
            float a4 = max3f(sA0[12], sA0[13], sA0[14]);
            float b0 = max3f(sA1[0], sA1[1], sA1[2]);
            float b1 = max3f(sA1[3], sA1[4], sA1[5]);
            float b2 = max3f(sA1[6], sA1[7], sA1[8]);
            float b3 = max3f(sA1[9], sA1[10], sA1[11]);
            float b4 = max3f(sA1[12], sA1[13], sA1[14]);
            float c0 = max3f(a0, a1, a2);
            float c1 = max3f(a3, a4, sA0[15]);
            float c2 = max3f(b0, b1, b2);
            float c3 = max3f(b3, b4, sA1[15]);
            float tm = xhalf_max(fmaxf(max3f(c0, c1, c2), c3));
            bool nore = __all(tm <= mA + 8.0f);
            if (!nore) {
                float nm = fmaxf(mA, tm);
                float al = fexp2(mA - nm);
                #pragma unroll
                for (int r = 0; r < 8; ++r) lacc[r] *= al;   // qsetA rows 0-15
                #pragma unroll
                for (int r = 0; r < 16; ++r) { ctxA[0][r] *= al; ctxA[1][r] *= al; }
                mA = nm;
            }
            #pragma unroll
            for (int r = 0; r < 16; ++r) { sA0[r] = fexp2(sA0[r] - mA); sA1[r] = fexp2(sA1[r] - mA); }
        }
        // ---- softmax qsetB ----
        {
            float a0 = max3f(sB0[0], sB0[1], sB0[2]);
            float a1 = max3f(sB0[3], sB0[4], sB0[5]);
            float a2 = max3f(sB0[6], sB0[7], sB0[8]);
            float a3 = max3f(sB0[9], sB0[10], sB0[11]);
            float a4 = max3f(sB0[12], sB0[13], sB0[14]);
            float b0 = max3f(sB1[0], sB1[1], sB1[2]);
            float b1 = max3f(sB1[3], sB1[4], sB1[5]);
            float b2 = max3f(sB1[6], sB1[7], sB1[8]);
            float b3 = max3f(sB1[9], sB1[10], sB1[11]);
            float b4 = max3f(sB1[12], sB1[13], sB1[14]);
            float c0 = max3f(a0, a1, a2);
            float c1 = max3f(a3, a4, sB0[15]);
            float c2 = max3f(b0, b1, b2);
            float c3 = max3f(b3, b4, sB1[15]);
            float tm = xhalf_max(fmaxf(max3f(c0, c1, c2), c3));
            bool nore = __all(tm <= mB + 8.0f);
            if (!nore) {
                float nm = fmaxf(mB, tm);
                float al = fexp2(mB - nm);
                #pragma unroll
                for (int r = 8; r < 16; ++r) lacc[r] *= al;  // qsetB rows 16-31
                #pragma unroll
                for (int r = 0; r < 16; ++r) { ctxB[0][r] *= al; ctxB[1][r] *= al; }
                mB = nm;
            }
            #pragma unroll
            for (int r = 0; r < 16; ++r) { sB0[r] = fexp2(sB0[r] - mB); sB1[r] = fexp2(sB1[r] - mB); }
        }

        // ---- P -> bf16 B-frags in-register (both qsets) ----
        u32 wA0[8], wA1[8], wB0[8], wB1[8];
        #pragma unroll
        for (int j = 0; j < 8; ++j) {
            wA0[j] = cvtpk(sA0[2 * j], sA0[2 * j + 1]);
            wA1[j] = cvtpk(sA1[2 * j], sA1[2 * j + 1]);
            wB0[j] = cvtpk(sB0[2 * j], sB0[2 * j + 1]);
            wB1[j] = cvtpk(sB1[2 * j], sB1[2 * j + 1]);
        }
        pl32swap(wA0[0], wA0[2]); pl32swap(wA0[1], wA0[3]);
        pl32swap(wA0[4], wA0[6]); pl32swap(wA0[5], wA0[7]);
        pl32swap(wA1[0], wA1[2]); pl32swap(wA1[1], wA1[3]);
        pl32swap(wA1[4], wA1[6]); pl32swap(wA1[5], wA1[7]);
        pl32swap(wB0[0], wB0[2]); pl32swap(wB0[1], wB0[3]);
        pl32swap(wB0[4], wB0[6]); pl32swap(wB0[5], wB0[7]);
        pl32swap(wB1[0], wB1[2]); pl32swap(wB1[1], wB1[3]);
        pl32swap(wB1[4], wB1[6]); pl32swap(wB1[5], wB1[7]);
        short8 pfA[4], pfB[4];
        {
            u32x4 t0; t0[0] = wA0[0]; t0[1] = wA0[1]; t0[2] = wA0[2]; t0[3] = wA0[3];
            u32x4 t1; t1[0] = wA0[4]; t1[1] = wA0[5]; t1[2] = wA0[6]; t1[3] = wA0[7];
            u32x4 t2; t2[0] = wA1[0]; t2[1] = wA1[1]; t2[2] = wA1[2]; t2[3] = wA1[3];
            u32x4 t3; t3[0] = wA1[4]; t3[1] = wA1[5]; t3[2] = wA1[6]; t3[3] = wA1[7];
            pfA[0] = __builtin_bit_cast(short8, t0);
            pfA[1] = __builtin_bit_cast(short8, t1);
            pfA[2] = __builtin_bit_cast(short8, t2);
            pfA[3] = __builtin_bit_cast(short8, t3);
            u32x4 u0; u0[0] = wB0[0]; u0[1] = wB0[1]; u0[2] = wB0[2]; u0[3] = wB0[3];
            u32x4 u1; u1[0] = wB0[4]; u1[1] = wB0[5]; u1[2] = wB0[6]; u1[3] = wB0[7];
            u32x4 u2; u2[0] = wB1[0]; u2[1] = wB1[1]; u2[2] = wB1[2]; u2[3] = wB1[3];
            u32x4 u3; u3[0] = wB1[4]; u3[1] = wB1[5]; u3[2] = wB1[6]; u3[3] = wB1[7];
            pfB[0] = __builtin_bit_cast(short8, u0);
            pfB[1] = __builtin_bit_cast(short8, u1);
            pfB[2] = __builtin_bit_cast(short8, u2);
            pfB[3] = __builtin_bit_cast(short8, u3);
        }

        // ---- PV + l-accumulation: V-frags shared across qsets ----
        __builtin_amdgcn_s_setprio(1);
        #pragma unroll
        for (int j = 0; j < 4; ++j) {
            lacc = __builtin_amdgcn_mfma_f32_32x32x16_bf16(aoneLo, pfA[j], lacc, 0, 0, 0);
            lacc = __builtin_amdgcn_mfma_f32_32x32x16_bf16(aoneHi, pfB[j], lacc, 0, 0, 0);
        }
        #pragma unroll
        for (int dt = 0; dt < 2; ++dt) {
            int vrow = dt * 32 + q;
            const u16* vb = Vc + vrow * 64;
            int sw = vrow & 7;
            #pragma unroll
            for (int j = 0; j < 4; ++j) {
                short8 vf = ld8(vb + (((2 * j + hf) ^ sw) * 8));
                ctxA[dt] = __builtin_amdgcn_mfma_f32_32x32x16_bf16(vf, pfA[j], ctxA[dt], 0, 0, 0);
                ctxB[dt] = __builtin_amdgcn_mfma_f32_32x32x16_bf16(vf, pfB[j], ctxB[dt], 0, 0, 0);
            }
        }
        __builtin_amdgcn_s_setprio(0);
        cur ^= 1;
    }

    // ---- epilogue: write unnormalized partials (both qsets) ----
    int qgA = qrow0 + q, qgB = qrow0 + 32 + q;
    if (hf == 0) {
        pm[(size_t)pg * Nn + qgA] = mA;
        pl[(size_t)pg * Nn + qgA] = lacc[0];   // qsetA rows 0-15
        pm[(size_t)pg * Nn + qgB] = mB;
        pl[(size_t)pg * Nn + qgB] = lacc[8];   // qsetB rows 16-31
    }
    #pragma unroll
    for (int dt = 0; dt < 2; ++dt) {
        #pragma unroll
        for (int r = 0; r < 16; ++r) {
            int d = dt * 32 + (r & 3) + 8 * (r >> 2) + 4 * hf;
            pc[((size_t)pg * 64 + d) * Nn + qgA] = f2bf(ctxA[dt][r]);
            pc[((size_t)pg * 64 + d) * Nn + qgB] = f2bf(ctxB[dt][r]);
        }
    }
}

// ---------------- merge: combine 4 KV-quarters, transpose to ctx layout ----------------
__global__ __launch_bounds__(256) void merge_kernel(
        const u16* __restrict__ pc, const float* __restrict__ pm,
        const float* __restrict__ pl, u16* __restrict__ ctxOut) {
    __shared__ float trans[64][65];
    __shared__ float fw[4][64];
    int bh = blockIdx.x >> 6;
    int q0 = (blockIdx.x & 63) * 64;
    int t = threadIdx.x;
    if (t < 64) {
        int qg = q0 + t;
        float m0 = pm[(size_t)(bh) * Nn + qg];
        float m1 = pm[(size_t)(16 + bh) * Nn + qg];
        float m2 = pm[(size_t)(32 + bh) * Nn + qg];
        float m3 = pm[(size_t)(48 + bh) * Nn + qg];
        float M = fmaxf(fmaxf(m0, m1), fmaxf(m2, m3));
        float w0 = fexp2(m0 - M), w1 = fexp2(m1 - M);
        float w2 = fexp2(m2 - M), w3 = fexp2(m3 - M);
        float l = pl[(size_t)(bh) * Nn + qg] * w0
                + pl[(size_t)(16 + bh) * Nn + qg] * w1
                + pl[(size_t)(32 + bh) * Nn + qg] * w2
                + pl[(size_t)(48 + bh) * Nn + qg] * w3;
        float inv = 1.0f / l;
        fw[0][t] = w0 * inv; fw[1][t] = w1 * inv;
        fw[2][t] = w2 * inv; fw[3][t] = w3 * inv;
    }
    __syncthreads();
    int wv = t >> 6, lane = t & 63;
    #pragma unroll
    for (int i = 0; i < 16; ++i) {
        int d = wv * 16 + i;
        float acc = 0.f;
        #pragma unroll
        for (int j = 0; j < 4; ++j) {
            float c = __uint_as_float((u32)pc[((size_t)(j * 16 + bh) * 64 + d) * Nn + q0 + lane] << 16);
            acc += c * fw[j][lane];
        }
        trans[lane][d] = acc;
    }
    __syncthreads();
    int q = t >> 2, dg = t & 3;
    int b = bh >> 2, h = bh & 3;
    const float* tr = &trans[q][dg * 16];
    uint4 pa, pb;
    pa.x = cvtpk(tr[0], tr[1]);  pa.y = cvtpk(tr[2], tr[3]);
    pa.z = cvtpk(tr[4], tr[5]);  pa.w = cvtpk(tr[6], tr[7]);
    pb.x = cvtpk(tr[8], tr[9]);  pb.y = cvtpk(tr[10], tr[11]);
    pb.z = cvtpk(tr[12], tr[13]); pb.w = cvtpk(tr[14], tr[15]);
    u16* op = ctxOut + ((size_t)b * Nn + q0 + q) * Dd + h * 64 + dg * 16;
    *(uint4*)op = pa;
    *(uint4*)(op + 8) = pb;
}

extern "C" void kernel_launch(void* const* d_in, const int* in_sizes, int n_in,
                              void* d_out, int out_size, void* d_ws, size_t ws_size,
                              hipStream_t stream) {
    (void)in_sizes; (void)n_in; (void)out_size; (void)ws_size;
    const float* tokens     = (const float*)d_in[0];
    const float* importance = (const float*)d_in[1];
    const float* n1w = (const float*)d_in[2];
    const float* n1b = (const float*)d_in[3];
    const float* Wq  = (const float*)d_in[4];
    const float* bq  = (const float*)d_in[5];
    const float* Wk  = (const float*)d_in[6];
    const float* bk  = (const float*)d_in[7];
    const float* Wv  = (const float*)d_in[8];
    const float* bv  = (const float*)d_in[9];
    const float* Wo  = (const float*)d_in[10];
    const float* bo  = (const float*)d_in[11];
    const float* n2w = (const float*)d_in[12];
    const float* n2b = (const float*)d_in[13];
    const float* W1  = (const float*)d_in[14];
    const float* b1  = (const float*)d_in[15];
    const float* W2  = (const float*)d_in[16];
    const float* b2  = (const float*)d_in[17];
    float* out = (float*)d_out;

    char* ws = (char*)d_ws;
    const size_t MB = (size_t)1 << 20;
    // Sequential reuse (single stream): yln reuses xln (dead after QKV GEMM);
    // hbuf reuses qb+kb (dead after attn); x2 = d_out (dead until out-proj).
    u16* xln   = (u16*)(ws);                    // 0..8MB   (later: yln)
    u16* qb    = (u16*)(ws + 8 * MB);           // 8..16MB  (later: hbuf lo)
    u16* kb    = (u16*)(ws + 16 * MB);          // 16..24MB (later: hbuf hi)
    u16* vT    = (u16*)(ws + 24 * MB);          // 24..32MB
    u16* ctx   = (u16*)(ws + 32 * MB);          // 32..40MB
    u16* pc    = (u16*)(ws + 40 * MB);          // 40..72MB [kvq*16+bh][64 d][4096 q]
    float* pm  = (float*)(ws + 72 * MB);        // 1MB
    float* pl  = (float*)(ws + 73 * MB);        // 1MB
    u16* WqkvT = (u16*)(ws + 74 * MB);          // 384KB
    u16* WoT   = (u16*)(ws + 74 * MB + 393216);
    u16* W1T   = (u16*)(ws + 74 * MB + 393216 + 131072);
    u16* W2T   = (u16*)(ws + 74 * MB + 393216 + 131072 + 262144);
    u32* impPk = (u32*)(ws + 74 * MB + 393216 + 131072 + 262144 + 262144);
    u16* yln   = xln;                           // reuse (xln dead after QKV)
    u16* hbuf  = qb;                            // reuse 16MB (qb+kb dead after attn)
    float* x2  = out;                           // reuse d_out as x2 scratch

    prep_kernel<<<2112, 256, 0, stream>>>(Wq, Wk, Wv, Wo, W1, W2, importance,
                                          WqkvT, WoT, W1T, W2T, impPk);
    ln_kernel<<<4096, 256, 0, stream>>>(tokens, n1w, n1b, xln);
    gemm_bt<0, 256, 128><<<dim3(6, 128), 256, 0, stream>>>(xln, WqkvT, bq, bk, bv,
                                                           nullptr, nullptr, qb, kb, vT);
    attn_kernel<<<1024, 256, 0, stream>>>(qb, kb, vT, impPk, pc, pm, pl);
    merge_kernel<<<1024, 256, 0, stream>>>(pc, pm, pl, ctx);
    oproj_ln_kernel<<<512, 256, 0, stream>>>(ctx, WoT, bo, tokens, n2w, n2b, x2, yln);
    gemm_bt<2, 256, 64><<<dim3(4, 256), 256, 0, stream>>>(yln, W1T, b1, nullptr, nullptr,
                                                          nullptr, nullptr, hbuf, nullptr, nullptr);
    gemm_bt<3, 512, 64><<<dim3(2, 256), 256, 0, stream>>>(hbuf, W2T, b2, nullptr, nullptr,
                                                          x2, out, nullptr, nullptr, nullptr);
}

// Round 16
// 182.780 us; speedup vs baseline: 3.4492x; 1.0574x over previous
//
#include <hip/hip_runtime.h>

#define Bb 4
#define Nn 4096
#define Dd 256
#define Hh 4
#define HDd 64
#define FFf 512
#define MT 16384  // B*N

typedef __attribute__((ext_vector_type(8))) short short8;
typedef __attribute__((ext_vector_type(4))) float f32x4;
typedef __attribute__((ext_vector_type(16))) float f32x16;
typedef unsigned short u16;
typedef unsigned int u32;
typedef __attribute__((ext_vector_type(4))) u32 u32x4;

typedef __attribute__((address_space(1))) const void glb_src;
typedef __attribute__((address_space(3))) void lds_dst;

__device__ __forceinline__ void gload_lds16(const void* g, void* l) {
    __builtin_amdgcn_global_load_lds((glb_src*)g, (lds_dst*)l, 16, 0, 0);
}

__device__ __forceinline__ u16 f2bf(float f) {
    union { float f; u32 i; } v; v.f = f;
    u32 r = v.i + 0x7FFFu + ((v.i >> 16) & 1u);
    return (u16)(r >> 16);
}

__device__ __forceinline__ short8 ld8(const u16* p) {
    return *(const short8*)p;
}

// v_permlane32_swap: a' = [a.lo, b.lo], b' = [a.hi, b.hi]
__device__ __forceinline__ void pl32swap(u32& a, u32& b) {
    asm("v_permlane32_swap_b32 %0, %1" : "+v"(a), "+v"(b));
}
__device__ __forceinline__ float xhalf_max(float x) {
    u32 a = __float_as_uint(x), b = a;
    pl32swap(a, b);
    return fmaxf(__uint_as_float(a), __uint_as_float(b));
}
__device__ __forceinline__ u32 cvtpk(float lo, float hi) {
    u32 r;
    asm("v_cvt_pk_bf16_f32 %0, %1, %2" : "=v"(r) : "v"(lo), "v"(hi));
    return r;
}
__device__ __forceinline__ float fexp2(float x) {
    float r;
    asm("v_exp_f32 %0, %1" : "=v"(r) : "v"(x));
    return r;
}
__device__ __forceinline__ float max3f(float a, float b, float c) {
    float r;
    asm("v_max3_f32 %0, %1, %2, %3" : "=v"(r) : "v"(a), "v"(b), "v"(c));
    return r;
}

#define QSCALE 0.18033610062f  /* 0.125 * log2(e) */
#define LOG2E  1.44269504089f

// ---------------- weight prep: transpose + bf16 cast + imp pack ----------------
__global__ __launch_bounds__(256) void prep_kernel(
        const float* __restrict__ Wq, const float* __restrict__ Wk,
        const float* __restrict__ Wv, const float* __restrict__ Wo,
        const float* __restrict__ W1, const float* __restrict__ W2,
        const float* __restrict__ imp,
        u16* __restrict__ WqkvT, u16* __restrict__ WoT,
        u16* __restrict__ W1T, u16* __restrict__ W2T,
        u32* __restrict__ impPk) {
    int e = blockIdx.x * 256 + threadIdx.x;
    if (e < 196608) {                    // 768*256
        int c = e >> 8, k = e & 255;
        int mat = c >> 8;                // 0=q,1=k,2=v
        int cc = c & 255;
        const float* W = (mat == 0) ? Wq : ((mat == 1) ? Wk : Wv);
        WqkvT[(size_t)c * 256 + k] = f2bf(W[k * 256 + cc]);
    } else if (e < 262144) {
        int i = e - 196608; int n = i >> 8, k = i & 255;
        WoT[n * 256 + k] = f2bf(Wo[k * 256 + n]);
    } else if (e < 393216) {
        int i = e - 262144; int n = i >> 8, k = i & 255;
        W1T[n * 256 + k] = f2bf(W1[k * 512 + n]);
    } else if (e < 524288) {
        int i = e - 393216; int n = i >> 9, k = i & 511;
        W2T[n * 512 + k] = f2bf(W2[k * 256 + n]);
    } else {
        int i = e - 524288;              // 0..16383 = B*N importance entries
        float ivs = imp[i] * LOG2E;
        u16 ih = f2bf(ivs);
        float rem = ivs - __uint_as_float(((u32)ih) << 16);
        u16 il = f2bf(rem);
        impPk[i] = ((u32)il << 16) | ih;
    }
}

// ---------------- LayerNorm ----------------
__global__ __launch_bounds__(256) void ln_kernel(const float* __restrict__ x,
        const float* __restrict__ w, const float* __restrict__ bia,
        u16* __restrict__ out) {
    int lane = threadIdx.x & 63;
    int row = blockIdx.x * 4 + (threadIdx.x >> 6);
    const float* xr = x + (size_t)row * Dd;
    float4 v = *(const float4*)(xr + lane * 4);
    float s = v.x + v.y + v.z + v.w;
    float s2 = v.x * v.x + v.y * v.y + v.z * v.z + v.w * v.w;
    #pragma unroll
    for (int off = 1; off < 64; off <<= 1) {
        s  += __shfl_xor(s, off);
        s2 += __shfl_xor(s2, off);
    }
    float mu = s * (1.0f / Dd);
    float var = s2 * (1.0f / Dd) - mu * mu;
    float rstd = rsqrtf(var + 1e-5f);
    float4 wv = *(const float4*)(w + lane * 4);
    float4 bv = *(const float4*)(bia + lane * 4);
    ushort4 ov;
    ov.x = f2bf((v.x - mu) * rstd * wv.x + bv.x);
    ov.y = f2bf((v.y - mu) * rstd * wv.y + bv.y);
    ov.z = f2bf((v.z - mu) * rstd * wv.z + bv.z);
    ov.w = f2bf((v.w - mu) * rstd * wv.w + bv.w);
    *(ushort4*)(out + (size_t)row * Dd + lane * 4) = ov;
}

// ---------------- GEMM: A[M,K] bf16 x BT[N,K] bf16 -> epilogue ----------------
template<int MODE, int KD, int BM>
__global__ __launch_bounds__(256) void gemm_bt(
        const u16* __restrict__ A, const u16* __restrict__ BT,
        const float* __restrict__ bias0, const float* __restrict__ bias1,
        const float* __restrict__ bias2,
        const float* __restrict__ resid, float* __restrict__ outf,
        u16* __restrict__ o0, u16* __restrict__ o1, u16* __restrict__ o2) {
    constexpr int AM = BM / 32;          // A-frags per wave (4 or 2)
    __shared__ u16 Asl[BM * 32];
    __shared__ u16 Bsl[128 * 32];
    int lane = threadIdx.x & 63;
    int wv = threadIdx.x >> 6;
    int wm = wv >> 1, wn = wv & 1;
    int m0 = blockIdx.y * BM, n0 = blockIdx.x * 128;
    f32x4 zz; zz[0] = 0.f; zz[1] = 0.f; zz[2] = 0.f; zz[3] = 0.f;
    f32x4 acc[AM][4];
    #pragma unroll
    for (int i = 0; i < AM; ++i)
        #pragma unroll
        for (int j = 0; j < 4; ++j) acc[i][j] = zz;

    for (int kt = 0; kt < KD; kt += 32) {
        __syncthreads();
        #pragma unroll
        for (int i = 0; i < BM / 64; ++i) {      // A: BM*4 16B-chunks
            int chunk = threadIdx.x + i * 256;
            int row = chunk >> 2, c16 = chunk & 3;
            int srcc = (c16 ^ (row & 3)) * 8;
            gload_lds16(A + (size_t)(m0 + row) * KD + kt + srcc,
                        (char*)Asl + wv * 1024 + i * 4096);
        }
        #pragma unroll
        for (int i = 0; i < 2; ++i) {            // B: 512 16B-chunks
            int chunk = threadIdx.x + i * 256;
            int row = chunk >> 2, c16 = chunk & 3;
            int srcc = (c16 ^ (row & 3)) * 8;
            gload_lds16(BT + (size_t)(n0 + row) * KD + kt + srcc,
                        (char*)Bsl + wv * 1024 + i * 4096);
        }
        __syncthreads();
        short8 af[AM], bfr[4];
        #pragma unroll
        for (int t = 0; t < AM; ++t) {
            int arow = wm * (BM / 2) + t * 16 + (lane & 15);
            af[t] = ld8(Asl + arow * 32 + (((lane >> 4) * 8) ^ ((arow & 3) * 8)));
        }
        #pragma unroll
        for (int t = 0; t < 4; ++t) {
            int brow = wn * 64 + t * 16 + (lane & 15);
            bfr[t] = ld8(Bsl + brow * 32 + (((lane >> 4) * 8) ^ ((brow & 3) * 8)));
        }
        #pragma unroll
        for (int mt = 0; mt < AM; ++mt)
            #pragma unroll
            for (int nt = 0; nt < 4; ++nt)
                acc[mt][nt] = __builtin_amdgcn_mfma_f32_16x16x32_bf16(af[mt], bfr[nt], acc[mt][nt], 0, 0, 0);
    }

    #pragma unroll
    for (int mt = 0; mt < AM; ++mt) {
        #pragma unroll
        for (int nt = 0; nt < 4; ++nt) {
            #pragma unroll
            for (int r = 0; r < 4; ++r) {
                int row = m0 + wm * (BM / 2) + mt * 16 + (lane >> 4) * 4 + r;
                int col = n0 + wn * 64 + nt * 16 + (lane & 15);
                float v = acc[mt][nt][r];
                if (MODE == 0) {
                    int mat = col >> 8;
                    int cc = col & 255;
                    int hh = cc >> 6, dd = cc & 63;
                    int bbi = row >> 12, nni = row & 4095;
                    int bh = bbi * Hh + hh;
                    // q pre-scaled by 0.125*log2(e) for exp2-domain flash attention
                    if (mat == 0)      o0[((size_t)bh * Nn + nni) * HDd + dd] = f2bf((v + bias0[cc]) * QSCALE);
                    else if (mat == 1) o1[((size_t)bh * Nn + nni) * HDd + dd] = f2bf(v + bias1[cc]);
                    else               o2[((size_t)bh * HDd + dd) * Nn + nni] = f2bf(v + bias2[cc]);
                } else if (MODE == 2) {
                    float xg = v + bias0[col];
                    float g = 0.5f * xg * (1.0f + erff(xg * 0.70710678118654752f));
                    o0[(size_t)row * FFf + col] = f2bf(g);
                } else {
                    outf[(size_t)row * Dd + col] = resid[(size_t)row * Dd + col] + v + bias0[col];
                }
            }
        }
    }
}

// ---------------- out-proj + residual + LayerNorm2 fused ----------------
__global__ __launch_bounds__(256) void oproj_ln_kernel(
        const u16* __restrict__ A, const u16* __restrict__ BT,
        const float* __restrict__ bias, const float* __restrict__ resid,
        const float* __restrict__ lnw, const float* __restrict__ lnb,
        float* __restrict__ x2, u16* __restrict__ yln) {
    __shared__ u16 Asl[32 * 32];
    __shared__ u16 Bsl[256 * 32];
    __shared__ float xlds[32][256];
    int lane = threadIdx.x & 63;
    int wv = threadIdx.x >> 6;
    int m0 = blockIdx.x * 32;
    f32x4 zz; zz[0] = 0.f; zz[1] = 0.f; zz[2] = 0.f; zz[3] = 0.f;
    f32x4 acc[2][4];
    #pragma unroll
    for (int i = 0; i < 2; ++i)
        #pragma unroll
        for (int j = 0; j < 4; ++j) acc[i][j] = zz;

    for (int kt = 0; kt < Dd; kt += 32) {
        __syncthreads();
        if (wv < 2) {                            // A: 128 16B-chunks
            int t = threadIdx.x;
            int row = t >> 2, c16 = t & 3;
            int srcc = (c16 ^ (row & 3)) * 8;
            gload_lds16(A + (size_t)(m0 + row) * Dd + kt + srcc,
                        (char*)Asl + wv * 1024);
        }
        #pragma unroll
        for (int i = 0; i < 4; ++i) {            // B: 1024 16B-chunks (all 256 rows)
            int chunk = threadIdx.x + i * 256;
            int row = chunk >> 2, c16 = chunk & 3;
            int srcc = (c16 ^ (row & 3)) * 8;
            gload_lds16(BT + (size_t)row * Dd + kt + srcc,
                        (char*)Bsl + wv * 1024 + i * 4096);
        }
        __syncthreads();
        short8 af[2], bfr[4];
        #pragma unroll
        for (int t = 0; t < 2; ++t) {
            int arow = t * 16 + (lane & 15);
            af[t] = ld8(Asl + arow * 32 + (((lane >> 4) * 8) ^ ((arow & 3) * 8)));
        }
        #pragma unroll
        for (int t = 0; t < 4; ++t) {
            int brow = wv * 64 + t * 16 + (lane & 15);
            bfr[t] = ld8(Bsl + brow * 32 + (((lane >> 4) * 8) ^ ((brow & 3) * 8)));
        }
        #pragma unroll
        for (int mt = 0; mt < 2; ++mt)
            #pragma unroll
            for (int nt = 0; nt < 4; ++nt)
                acc[mt][nt] = __builtin_amdgcn_mfma_f32_16x16x32_bf16(af[mt], bfr[nt], acc[mt][nt], 0, 0, 0);
    }

    // epilogue: x2 = resid + acc + bias -> global + LDS
    #pragma unroll
    for (int mt = 0; mt < 2; ++mt) {
        #pragma unroll
        for (int nt = 0; nt < 4; ++nt) {
            #pragma unroll
            for (int r = 0; r < 4; ++r) {
                int row = mt * 16 + (lane >> 4) * 4 + r;
                int col = wv * 64 + nt * 16 + (lane & 15);
                float v = resid[(size_t)(m0 + row) * Dd + col] + acc[mt][nt][r] + bias[col];
                x2[(size_t)(m0 + row) * Dd + col] = v;
                xlds[row][col] = v;
            }
        }
    }
    __syncthreads();

    // LN over full rows: 8 threads/row, 32 cols each
    int rw = threadIdx.x >> 3;
    int cg = (threadIdx.x & 7) * 32;
    float s = 0.f, s2 = 0.f;
    #pragma unroll
    for (int j = 0; j < 32; ++j) {
        float v = xlds[rw][cg + j];
        s += v; s2 += v * v;
    }
    #pragma unroll
    for (int off = 1; off < 8; off <<= 1) {
        s  += __shfl_xor(s, off);
        s2 += __shfl_xor(s2, off);
    }
    float mu = s * (1.0f / Dd);
    float var = s2 * (1.0f / Dd) - mu * mu;
    float rstd = rsqrtf(var + 1e-5f);
    u16* op = yln + (size_t)(m0 + rw) * Dd + cg;
    #pragma unroll
    for (int j = 0; j < 32; j += 8) {
        float v0 = (xlds[rw][cg + j + 0] - mu) * rstd * lnw[cg + j + 0] + lnb[cg + j + 0];
        float v1 = (xlds[rw][cg + j + 1] - mu) * rstd * lnw[cg + j + 1] + lnb[cg + j + 1];
        float v2 = (xlds[rw][cg + j + 2] - mu) * rstd * lnw[cg + j + 2] + lnb[cg + j + 2];
        float v3 = (xlds[rw][cg + j + 3] - mu) * rstd * lnw[cg + j + 3] + lnb[cg + j + 3];
        float v4 = (xlds[rw][cg + j + 4] - mu) * rstd * lnw[cg + j + 4] + lnb[cg + j + 4];
        float v5 = (xlds[rw][cg + j + 5] - mu) * rstd * lnw[cg + j + 5] + lnb[cg + j + 5];
        float v6 = (xlds[rw][cg + j + 6] - mu) * rstd * lnw[cg + j + 6] + lnb[cg + j + 6];
        float v7 = (xlds[rw][cg + j + 7] - mu) * rstd * lnw[cg + j + 7] + lnb[cg + j + 7];
        uint4 pk;
        pk.x = cvtpk(v0, v1); pk.y = cvtpk(v2, v3);
        pk.z = cvtpk(v4, v5); pk.w = cvtpk(v6, v7);
        *(uint4*)(op + j) = pk;
    }
}

// ---------------- Flash attention, KV-split x2, 2-qset waves ----------------
// grid: 2 halves x 16 bh x 16 qt(256). 4 waves x 64 q-rows (two 32-q sets).
// K/V frags load once per tile, feed both qsets (halves LDS reads per q);
// qsetA softmax overlaps qsetB QK^T (in-wave ILP). Single lacc via row-split
// all-ones A-frags (rows 0-15 = qsetA sums, rows 16-31 = qsetB).
__global__ __launch_bounds__(256, 2) void attn_kernel(
        const u16* __restrict__ Qb, const u16* __restrict__ Kb,
        const u16* __restrict__ VTb, const u32* __restrict__ impPk,
        u16* __restrict__ pc, float* __restrict__ pm, float* __restrict__ pl) {
    __shared__ u16 Klds[2][64 * 64];
    __shared__ u16 Vlds[2][64 * 64];
    int lane = threadIdx.x & 63;
    int wv = threadIdx.x >> 6;
    int kvh = blockIdx.x >> 8;
    int bh = (blockIdx.x >> 4) & 15;
    int qt = blockIdx.x & 15;
    int bbi = bh >> 2;
    int qrow0 = qt * 256 + wv * 64;
    int q = lane & 31;
    int hf = lane >> 5;
    int key0 = kvh * 2048;
    int pg = kvh * 16 + bh;

    // Q B-frags, two qsets
    short8 qfA[4], qfB[4];
    #pragma unroll
    for (int ks = 0; ks < 4; ++ks) {
        qfA[ks] = ld8(Qb + ((size_t)bh * Nn + qrow0 + q) * HDd + ks * 16 + hf * 8);
        qfB[ks] = ld8(Qb + ((size_t)bh * Nn + qrow0 + 32 + q) * HDd + ks * 16 + hf * 8);
    }

    // B-frag with ones at k=0,1 (importance augmentation)
    short8 onef = (short8)0;
    if (hf == 0) { onef[0] = (short)0x3F80; onef[1] = (short)0x3F80; }
    // row-split all-ones A-frags: aoneLo -> rows 0-15 (qsetA), aoneHi -> 16-31
    short8 aoneLo = (short8)0, aoneHi = (short8)0;
    if ((lane & 31) < 16) {
        #pragma unroll
        for (int j = 0; j < 8; ++j) aoneLo[j] = (short)0x3F80;
    } else {
        #pragma unroll
        for (int j = 0; j < 8; ++j) aoneHi[j] = (short)0x3F80;
    }

    // staging: lane covers LDS row base+(l>>3), slot l&7; source pre-swizzled
    int sr = lane >> 3;
    int sc = lane & 7;
    int swz = (sc ^ sr) * 8;
    const u16* kp = Kb + ((size_t)bh * Nn + key0 + wv * 16 + sr) * HDd + swz;
    const u16* vp = VTb + ((size_t)bh * HDd + wv * 16 + sr) * Nn + key0 + swz;
    size_t ib = (size_t)bbi * Nn;

    gload_lds16(kp,           (char*)Klds[0] + wv * 2048);
    gload_lds16(kp + 8 * HDd, (char*)Klds[0] + wv * 2048 + 1024);
    gload_lds16(vp,           (char*)Vlds[0] + wv * 2048);
    gload_lds16(vp + 8 * Nn,  (char*)Vlds[0] + wv * 2048 + 1024);
    kp += 64 * HDd; vp += 64;
    u32 npk0 = impPk[ib + key0 + q], npk1 = impPk[ib + key0 + 32 + q];

    f32x16 ctxA[2], ctxB[2], lacc;
    #pragma unroll
    for (int r = 0; r < 16; ++r) {
        ctxA[0][r] = 0.f; ctxA[1][r] = 0.f;
        ctxB[0][r] = 0.f; ctxB[1][r] = 0.f;
        lacc[r] = 0.f;
    }
    float mA = -__builtin_inff(), mB = -__builtin_inff();

    int cur = 0;
    for (int t = 0; t < 32; ++t) {
        __syncthreads();   // buf[cur] ready; buf[cur^1] free
        u32 pk0 = npk0, pk1 = npk1;
        if (t < 31) {
            gload_lds16(kp,           (char*)Klds[cur ^ 1] + wv * 2048);
            gload_lds16(kp + 8 * HDd, (char*)Klds[cur ^ 1] + wv * 2048 + 1024);
            gload_lds16(vp,           (char*)Vlds[cur ^ 1] + wv * 2048);
            gload_lds16(vp + 8 * Nn,  (char*)Vlds[cur ^ 1] + wv * 2048 + 1024);
            kp += 64 * HDd; vp += 64;
            npk0 = impPk[ib + key0 + t * 64 + 64 + q];
            npk1 = impPk[ib + key0 + t * 64 + 96 + q];
        }
        const u16* Kc = Klds[cur];
        const u16* Vc = Vlds[cur];

        // ---- QK^T: K-frags shared across both qsets ----
        f32x16 sA0, sA1, sB0, sB1;
        #pragma unroll
        for (int r = 0; r < 16; ++r) { sA0[r] = 0.f; sA1[r] = 0.f; sB0[r] = 0.f; sB1[r] = 0.f; }
        __builtin_amdgcn_s_setprio(1);
        #pragma unroll
        for (int ks = 0; ks < 4; ++ks) {
            short8 kf0 = ld8(Kc + q * 64 + (((ks * 2 + hf) ^ (q & 7)) * 8));
            short8 kf1 = ld8(Kc + (32 + q) * 64 + (((ks * 2 + hf) ^ (q & 7)) * 8));
            sA0 = __builtin_amdgcn_mfma_f32_32x32x16_bf16(kf0, qfA[ks], sA0, 0, 0, 0);
            sA1 = __builtin_amdgcn_mfma_f32_32x32x16_bf16(kf1, qfA[ks], sA1, 0, 0, 0);
            sB0 = __builtin_amdgcn_mfma_f32_32x32x16_bf16(kf0, qfB[ks], sB0, 0, 0, 0);
            sB1 = __builtin_amdgcn_mfma_f32_32x32x16_bf16(kf1, qfB[ks], sB1, 0, 0, 0);
        }
        short8 af0 = (short8)0, af1 = (short8)0;
        if (hf == 0) {
            af0[0] = (short)(pk0 & 0xFFFFu); af0[1] = (short)(pk0 >> 16);
            af1[0] = (short)(pk1 & 0xFFFFu); af1[1] = (short)(pk1 >> 16);
        }
        sA0 = __builtin_amdgcn_mfma_f32_32x32x16_bf16(af0, onef, sA0, 0, 0, 0);
        sA1 = __builtin_amdgcn_mfma_f32_32x32x16_bf16(af1, onef, sA1, 0, 0, 0);
        sB0 = __builtin_amdgcn_mfma_f32_32x32x16_bf16(af0, onef, sB0, 0, 0, 0);
        sB1 = __builtin_amdgcn_mfma_f32_32x32x16_bf16(af1, onef, sB1, 0, 0, 0);
        __builtin_amdgcn_s_setprio(0);

        // ---- softmax qsetA ----
        {
            float a0 = max3f(sA0[0], sA0[1], sA0[2]);
            float a1 = max3f(sA0[3], sA0[4], sA0[5]);
            float a2 = max3f(sA0[6], sA0[7], sA0[8]);
            float a3 = max3f(sA0[9], sA0[10], sA0[11]);
            float a4 = max3f(sA0[12], sA0[13], sA0[14]);
            float b0 = max3f(sA1[0], sA1[1], sA1[2]);
            float b1 = max3f(sA1[3], sA1[4], sA1[5]);
            float b2 = max3f(sA1[6], sA1[7], sA1[8]);
            float b3 = max3f(sA1[9], sA1[10], sA1[11]);
            float b4 = max3f(sA1[12], sA1[13], sA1[14]);
            float c0 = max3f(a0, a1, a2);
            float c1 = max3f(a3, a4, sA0[15]);
            float c2 = max3f(b0, b1, b2);
            float c3 = max3f(b3, b4, sA1[15]);
            float tm = xhalf_max(fmaxf(max3f(c0, c1, c2), c3));
            bool nore = __all(tm <= mA + 8.0f);
            if (!nore) {
                float nm = fmaxf(mA, tm);
                float al = fexp2(mA - nm);
                #pragma unroll
                for (int r = 0; r < 8; ++r) lacc[r] *= al;   // qsetA rows 0-15
                #pragma unroll
                for (int r = 0; r < 16; ++r) { ctxA[0][r] *= al; ctxA[1][r] *= al; }
                mA = nm;
            }
            #pragma unroll
            for (int r = 0; r < 16; ++r) { sA0[r] = fexp2(sA0[r] - mA); sA1[r] = fexp2(sA1[r] - mA); }
        }
        // ---- softmax qsetB ----
        {
            float a0 = max3f(sB0[0], sB0[1], sB0[2]);
            float a1 = max3f(sB0[3], sB0[4], sB0[5]);
            float a2 = max3f(sB0[6], sB0[7], sB0[8]);
            float a3 = max3f(sB0[9], sB0[10], sB0[11]);
            float a4 = max3f(sB0[12], sB0[13], sB0[14]);
            float b0 = max3f(sB1[0], sB1[1], sB1[2]);
            float b1 = max3f(sB1[3], sB1[4], sB1[5]);
            float b2 = max3f(sB1[6], sB1[7], sB1[8]);
            float b3 = max3f(sB1[9], sB1[10], sB1[11]);
            float b4 = max3f(sB1[12], sB1[13], sB1[14]);
            float c0 = max3f(a0, a1, a2);
            float c1 = max3f(a3, a4, sB0[15]);
            float c2 = max3f(b0, b1, b2);
            float c3 = max3f(b3, b4, sB1[15]);
            float tm = xhalf_max(fmaxf(max3f(c0, c1, c2), c3));
            bool nore = __all(tm <= mB + 8.0f);
            if (!nore) {
                float nm = fmaxf(mB, tm);
                float al = fexp2(mB - nm);
                #pragma unroll
                for (int r = 8; r < 16; ++r) lacc[r] *= al;  // qsetB rows 16-31
                #pragma unroll
                for (int r = 0; r < 16; ++r) { ctxB[0][r] *= al; ctxB[1][r] *= al; }
                mB = nm;
            }
            #pragma unroll
            for (int r = 0; r < 16; ++r) { sB0[r] = fexp2(sB0[r] - mB); sB1[r] = fexp2(sB1[r] - mB); }
        }

        // ---- P -> bf16 B-frags in-register (both qsets) ----
        u32 wA0[8], wA1[8], wB0[8], wB1[8];
        #pragma unroll
        for (int j = 0; j < 8; ++j) {
            wA0[j] = cvtpk(sA0[2 * j], sA0[2 * j + 1]);
            wA1[j] = cvtpk(sA1[2 * j], sA1[2 * j + 1]);
            wB0[j] = cvtpk(sB0[2 * j], sB0[2 * j + 1]);
            wB1[j] = cvtpk(sB1[2 * j], sB1[2 * j + 1]);
        }
        pl32swap(wA0[0], wA0[2]); pl32swap(wA0[1], wA0[3]);
        pl32swap(wA0[4], wA0[6]); pl32swap(wA0[5], wA0[7]);
        pl32swap(wA1[0], wA1[2]); pl32swap(wA1[1], wA1[3]);
        pl32swap(wA1[4], wA1[6]); pl32swap(wA1[5], wA1[7]);
        pl32swap(wB0[0], wB0[2]); pl32swap(wB0[1], wB0[3]);
        pl32swap(wB0[4], wB0[6]); pl32swap(wB0[5], wB0[7]);
        pl32swap(wB1[0], wB1[2]); pl32swap(wB1[1], wB1[3]);
        pl32swap(wB1[4], wB1[6]); pl32swap(wB1[5], wB1[7]);
        short8 pfA[4], pfB[4];
        {
            u32x4 t0; t0[0] = wA0[0]; t0[1] = wA0[1]; t0[2] = wA0[2]; t0[3] = wA0[3];
            u32x4 t1; t1[0] = wA0[4]; t1[1] = wA0[5]; t1[2] = wA0[6]; t1[3] = wA0[7];
            u32x4 t2; t2[0] = wA1[0]; t2[1] = wA1[1]; t2[2] = wA1[2]; t2[3] = wA1[3];
            u32x4 t3; t3[0] = wA1[4]; t3[1] = wA1[5]; t3[2] = wA1[6]; t3[3] = wA1[7];
            pfA[0] = __builtin_bit_cast(short8, t0);
            pfA[1] = __builtin_bit_cast(short8, t1);
            pfA[2] = __builtin_bit_cast(short8, t2);
            pfA[3] = __builtin_bit_cast(short8, t3);
            u32x4 u0; u0[0] = wB0[0]; u0[1] = wB0[1]; u0[2] = wB0[2]; u0[3] = wB0[3];
            u32x4 u1; u1[0] = wB0[4]; u1[1] = wB0[5]; u1[2] = wB0[6]; u1[3] = wB0[7];
            u32x4 u2; u2[0] = wB1[0]; u2[1] = wB1[1]; u2[2] = wB1[2]; u2[3] = wB1[3];
            u32x4 u3; u3[0] = wB1[4]; u3[1] = wB1[5]; u3[2] = wB1[6]; u3[3] = wB1[7];
            pfB[0] = __builtin_bit_cast(short8, u0);
            pfB[1] = __builtin_bit_cast(short8, u1);
            pfB[2] = __builtin_bit_cast(short8, u2);
            pfB[3] = __builtin_bit_cast(short8, u3);
        }

        // ---- PV + l-accumulation: V-frags shared across qsets ----
        __builtin_amdgcn_s_setprio(1);
        #pragma unroll
        for (int j = 0; j < 4; ++j) {
            lacc = __builtin_amdgcn_mfma_f32_32x32x16_bf16(aoneLo, pfA[j], lacc, 0, 0, 0);
            lacc = __builtin_amdgcn_mfma_f32_32x32x16_bf16(aoneHi, pfB[j], lacc, 0, 0, 0);
        }
        #pragma unroll
        for (int dt = 0; dt < 2; ++dt) {
            int vrow = dt * 32 + q;
            const u16* vb = Vc + vrow * 64;
            int sw = vrow & 7;
            #pragma unroll
            for (int j = 0; j < 4; ++j) {
                short8 vf = ld8(vb + (((2 * j + hf) ^ sw) * 8));
                ctxA[dt] = __builtin_amdgcn_mfma_f32_32x32x16_bf16(vf, pfA[j], ctxA[dt], 0, 0, 0);
                ctxB[dt] = __builtin_amdgcn_mfma_f32_32x32x16_bf16(vf, pfB[j], ctxB[dt], 0, 0, 0);
            }
        }
        __builtin_amdgcn_s_setprio(0);
        cur ^= 1;
    }

    // ---- epilogue: write unnormalized partials (both qsets) ----
    int qgA = qrow0 + q, qgB = qrow0 + 32 + q;
    if (hf == 0) {
        pm[(size_t)pg * Nn + qgA] = mA;
        pl[(size_t)pg * Nn + qgA] = lacc[0];   // qsetA rows 0-15
        pm[(size_t)pg * Nn + qgB] = mB;
        pl[(size_t)pg * Nn + qgB] = lacc[8];   // qsetB rows 16-31
    }
    #pragma unroll
    for (int dt = 0; dt < 2; ++dt) {
        #pragma unroll
        for (int r = 0; r < 16; ++r) {
            int d = dt * 32 + (r & 3) + 8 * (r >> 2) + 4 * hf;
            pc[((size_t)pg * 64 + d) * Nn + qgA] = f2bf(ctxA[dt][r]);
            pc[((size_t)pg * 64 + d) * Nn + qgB] = f2bf(ctxB[dt][r]);
        }
    }
}

// ---------------- merge: combine 2 KV-halves, transpose to ctx layout ----------------
__global__ __launch_bounds__(256) void merge_kernel(
        const u16* __restrict__ pc, const float* __restrict__ pm,
        const float* __restrict__ pl, u16* __restrict__ ctxOut) {
    __shared__ float trans[64][65];
    __shared__ float f0a[64], f1a[64];
    int bh = blockIdx.x >> 6;
    int q0 = (blockIdx.x & 63) * 64;
    int t = threadIdx.x;
    if (t < 64) {
        int qg = q0 + t;
        float m0 = pm[(size_t)bh * Nn + qg];
        float m1 = pm[(size_t)(16 + bh) * Nn + qg];
        float l0 = pl[(size_t)bh * Nn + qg];
        float l1 = pl[(size_t)(16 + bh) * Nn + qg];
        float M = fmaxf(m0, m1);
        float w0 = fexp2(m0 - M), w1 = fexp2(m1 - M);
        float inv = 1.0f / (l0 * w0 + l1 * w1);
        f0a[t] = w0 * inv; f1a[t] = w1 * inv;
    }
    __syncthreads();
    int wv = t >> 6, lane = t & 63;
    #pragma unroll
    for (int i = 0; i < 16; ++i) {
        int d = wv * 16 + i;
        float c0 = __uint_as_float((u32)pc[((size_t)bh * 64 + d) * Nn + q0 + lane] << 16);
        float c1 = __uint_as_float((u32)pc[((size_t)(16 + bh) * 64 + d) * Nn + q0 + lane] << 16);
        trans[lane][d] = c0 * f0a[lane] + c1 * f1a[lane];
    }
    __syncthreads();
    int q = t >> 2, dg = t & 3;
    int b = bh >> 2, h = bh & 3;
    const float* tr = &trans[q][dg * 16];
    uint4 pa, pb;
    pa.x = cvtpk(tr[0], tr[1]);  pa.y = cvtpk(tr[2], tr[3]);
    pa.z = cvtpk(tr[4], tr[5]);  pa.w = cvtpk(tr[6], tr[7]);
    pb.x = cvtpk(tr[8], tr[9]);  pb.y = cvtpk(tr[10], tr[11]);
    pb.z = cvtpk(tr[12], tr[13]); pb.w = cvtpk(tr[14], tr[15]);
    u16* op = ctxOut + ((size_t)b * Nn + q0 + q) * Dd + h * 64 + dg * 16;
    *(uint4*)op = pa;
    *(uint4*)(op + 8) = pb;
}

extern "C" void kernel_launch(void* const* d_in, const int* in_sizes, int n_in,
                              void* d_out, int out_size, void* d_ws, size_t ws_size,
                              hipStream_t stream) {
    (void)in_sizes; (void)n_in; (void)out_size; (void)ws_size;
    const float* tokens     = (const float*)d_in[0];
    const float* importance = (const float*)d_in[1];
    const float* n1w = (const float*)d_in[2];
    const float* n1b = (const float*)d_in[3];
    const float* Wq  = (const float*)d_in[4];
    const float* bq  = (const float*)d_in[5];
    const float* Wk  = (const float*)d_in[6];
    const float* bk  = (const float*)d_in[7];
    const float* Wv  = (const float*)d_in[8];
    const float* bv  = (const float*)d_in[9];
    const float* Wo  = (const float*)d_in[10];
    const float* bo  = (const float*)d_in[11];
    const float* n2w = (const float*)d_in[12];
    const float* n2b = (const float*)d_in[13];
    const float* W1  = (const float*)d_in[14];
    const float* b1  = (const float*)d_in[15];
    const float* W2  = (const float*)d_in[16];
    const float* b2  = (const float*)d_in[17];
    float* out = (float*)d_out;

    char* ws = (char*)d_ws;
    const size_t MB = (size_t)1 << 20;
    // Sequential reuse (single stream): yln reuses xln (dead after QKV GEMM);
    // hbuf reuses qb+kb (dead after attn); x2 = d_out (dead until out-proj).
    u16* xln   = (u16*)(ws);                    // 0..8MB   (later: yln)
    u16* qb    = (u16*)(ws + 8 * MB);           // 8..16MB  (later: hbuf lo)
    u16* kb    = (u16*)(ws + 16 * MB);          // 16..24MB (later: hbuf hi)
    u16* vT    = (u16*)(ws + 24 * MB);          // 24..32MB
    u16* ctx   = (u16*)(ws + 32 * MB);          // 32..40MB
    u16* pc    = (u16*)(ws + 40 * MB);          // 40..56MB [kvh*16+bh][64 d][4096 q]
    float* pm  = (float*)(ws + 56 * MB);        // 512KB
    float* pl  = (float*)(ws + 56 * MB + 524288);
    u16* WqkvT = (u16*)(ws + 57 * MB);          // 384KB
    u16* WoT   = (u16*)(ws + 57 * MB + 393216);
    u16* W1T   = (u16*)(ws + 57 * MB + 393216 + 131072);
    u16* W2T   = (u16*)(ws + 57 * MB + 393216 + 131072 + 262144);
    u32* impPk = (u32*)(ws + 57 * MB + 393216 + 131072 + 262144 + 262144);
    u16* yln   = xln;                           // reuse (xln dead after QKV)
    u16* hbuf  = qb;                            // reuse 16MB (qb+kb dead after attn)
    float* x2  = out;                           // reuse d_out as x2 scratch

    prep_kernel<<<2112, 256, 0, stream>>>(Wq, Wk, Wv, Wo, W1, W2, importance,
                                          WqkvT, WoT, W1T, W2T, impPk);
    ln_kernel<<<4096, 256, 0, stream>>>(tokens, n1w, n1b, xln);
    gemm_bt<0, 256, 128><<<dim3(6, 128), 256, 0, stream>>>(xln, WqkvT, bq, bk, bv,
                                                           nullptr, nullptr, qb, kb, vT);
    attn_kernel<<<512, 256, 0, stream>>>(qb, kb, vT, impPk, pc, pm, pl);
    merge_kernel<<<1024, 256, 0, stream>>>(pc, pm, pl, ctx);
    oproj_ln_kernel<<<512, 256, 0, stream>>>(ctx, WoT, bo, tokens, n2w, n2b, x2, yln);
    gemm_bt<2, 256, 64><<<dim3(4, 256), 256, 0, stream>>>(yln, W1T, b1, nullptr, nullptr,
                                                          nullptr, nullptr, hbuf, nullptr, nullptr);
    gemm_bt<3, 512, 64><<<dim3(2, 256), 256, 0, stream>>>(hbuf, W2T, b2, nullptr, nullptr,
                                                          x2, out, nullptr, nullptr, nullptr);
}

// Round 17
// 182.209 us; speedup vs baseline: 3.4600x; 1.0031x over previous
//
#include <hip/hip_runtime.h>

#define Bb 4
#define Nn 4096
#define Dd 256
#define Hh 4
#define HDd 64
#define FFf 512
#define MT 16384  // B*N

typedef __attribute__((ext_vector_type(8))) short short8;
typedef __attribute__((ext_vector_type(4))) float f32x4;
typedef __attribute__((ext_vector_type(16))) float f32x16;
typedef unsigned short u16;
typedef unsigned int u32;
typedef __attribute__((ext_vector_type(4))) u32 u32x4;

typedef __attribute__((address_space(1))) const void glb_src;
typedef __attribute__((address_space(3))) void lds_dst;

__device__ __forceinline__ void gload_lds16(const void* g, void* l) {
    __builtin_amdgcn_global_load_lds((glb_src*)g, (lds_dst*)l, 16, 0, 0);
}

__device__ __forceinline__ u16 f2bf(float f) {
    union { float f; u32 i; } v; v.f = f;
    u32 r = v.i + 0x7FFFu + ((v.i >> 16) & 1u);
    return (u16)(r >> 16);
}

__device__ __forceinline__ short8 ld8(const u16* p) {
    return *(const short8*)p;
}

// v_permlane32_swap: a' = [a.lo, b.lo], b' = [a.hi, b.hi]
__device__ __forceinline__ void pl32swap(u32& a, u32& b) {
    asm("v_permlane32_swap_b32 %0, %1" : "+v"(a), "+v"(b));
}
__device__ __forceinline__ float xhalf_max(float x) {
    u32 a = __float_as_uint(x), b = a;
    pl32swap(a, b);
    return fmaxf(__uint_as_float(a), __uint_as_float(b));
}
__device__ __forceinline__ u32 cvtpk(float lo, float hi) {
    u32 r;
    asm("v_cvt_pk_bf16_f32 %0, %1, %2" : "=v"(r) : "v"(lo), "v"(hi));
    return r;
}
__device__ __forceinline__ float fexp2(float x) {
    float r;
    asm("v_exp_f32 %0, %1" : "=v"(r) : "v"(x));
    return r;
}
__device__ __forceinline__ float max3f(float a, float b, float c) {
    float r;
    asm("v_max3_f32 %0, %1, %2, %3" : "=v"(r) : "v"(a), "v"(b), "v"(c));
    return r;
}

#define QSCALE 0.18033610062f  /* 0.125 * log2(e) */
#define LOG2E  1.44269504089f

// ---------------- weight prep: transpose + bf16 cast + imp pack ----------------
__global__ __launch_bounds__(256) void prep_kernel(
        const float* __restrict__ Wq, const float* __restrict__ Wk,
        const float* __restrict__ Wv, const float* __restrict__ Wo,
        const float* __restrict__ W1, const float* __restrict__ W2,
        const float* __restrict__ imp,
        u16* __restrict__ WqkvT, u16* __restrict__ WoT,
        u16* __restrict__ W1T, u16* __restrict__ W2T,
        u32* __restrict__ impPk) {
    int e = blockIdx.x * 256 + threadIdx.x;
    if (e < 196608) {                    // 768*256
        int c = e >> 8, k = e & 255;
        int mat = c >> 8;                // 0=q,1=k,2=v
        int cc = c & 255;
        const float* W = (mat == 0) ? Wq : ((mat == 1) ? Wk : Wv);
        WqkvT[(size_t)c * 256 + k] = f2bf(W[k * 256 + cc]);
    } else if (e < 262144) {
        int i = e - 196608; int n = i >> 8, k = i & 255;
        WoT[n * 256 + k] = f2bf(Wo[k * 256 + n]);
    } else if (e < 393216) {
        int i = e - 262144; int n = i >> 8, k = i & 255;
        W1T[n * 256 + k] = f2bf(W1[k * 512 + n]);
    } else if (e < 524288) {
        int i = e - 393216; int n = i >> 9, k = i & 511;
        W2T[n * 512 + k] = f2bf(W2[k * 256 + n]);
    } else {
        int i = e - 524288;              // 0..16383 = B*N importance entries
        float ivs = imp[i] * LOG2E;
        u16 ih = f2bf(ivs);
        float rem = ivs - __uint_as_float(((u32)ih) << 16);
        u16 il = f2bf(rem);
        impPk[i] = ((u32)il << 16) | ih;
    }
}

// ---------------- LayerNorm ----------------
__global__ __launch_bounds__(256) void ln_kernel(const float* __restrict__ x,
        const float* __restrict__ w, const float* __restrict__ bia,
        u16* __restrict__ out) {
    int lane = threadIdx.x & 63;
    int row = blockIdx.x * 4 + (threadIdx.x >> 6);
    const float* xr = x + (size_t)row * Dd;
    float4 v = *(const float4*)(xr + lane * 4);
    float s = v.x + v.y + v.z + v.w;
    float s2 = v.x * v.x + v.y * v.y + v.z * v.z + v.w * v.w;
    #pragma unroll
    for (int off = 1; off < 64; off <<= 1) {
        s  += __shfl_xor(s, off);
        s2 += __shfl_xor(s2, off);
    }
    float mu = s * (1.0f / Dd);
    float var = s2 * (1.0f / Dd) - mu * mu;
    float rstd = rsqrtf(var + 1e-5f);
    float4 wv = *(const float4*)(w + lane * 4);
    float4 bv = *(const float4*)(bia + lane * 4);
    ushort4 ov;
    ov.x = f2bf((v.x - mu) * rstd * wv.x + bv.x);
    ov.y = f2bf((v.y - mu) * rstd * wv.y + bv.y);
    ov.z = f2bf((v.z - mu) * rstd * wv.z + bv.z);
    ov.w = f2bf((v.w - mu) * rstd * wv.w + bv.w);
    *(ushort4*)(out + (size_t)row * Dd + lane * 4) = ov;
}

// ---------------- GEMM: A[M,K] bf16 x BT[N,K] bf16 -> epilogue ----------------
template<int MODE, int KD, int BM>
__global__ __launch_bounds__(256) void gemm_bt(
        const u16* __restrict__ A, const u16* __restrict__ BT,
        const float* __restrict__ bias0, const float* __restrict__ bias1,
        const float* __restrict__ bias2,
        const float* __restrict__ resid, float* __restrict__ outf,
        u16* __restrict__ o0, u16* __restrict__ o1, u16* __restrict__ o2) {
    constexpr int AM = BM / 32;          // A-frags per wave (4 or 2)
    __shared__ u16 Asl[BM * 32];
    __shared__ u16 Bsl[128 * 32];
    int lane = threadIdx.x & 63;
    int wv = threadIdx.x >> 6;
    int wm = wv >> 1, wn = wv & 1;
    int m0 = blockIdx.y * BM, n0 = blockIdx.x * 128;
    f32x4 zz; zz[0] = 0.f; zz[1] = 0.f; zz[2] = 0.f; zz[3] = 0.f;
    f32x4 acc[AM][4];
    #pragma unroll
    for (int i = 0; i < AM; ++i)
        #pragma unroll
        for (int j = 0; j < 4; ++j) acc[i][j] = zz;

    for (int kt = 0; kt < KD; kt += 32) {
        __syncthreads();
        #pragma unroll
        for (int i = 0; i < BM / 64; ++i) {      // A: BM*4 16B-chunks
            int chunk = threadIdx.x + i * 256;
            int row = chunk >> 2, c16 = chunk & 3;
            int srcc = (c16 ^ (row & 3)) * 8;
            gload_lds16(A + (size_t)(m0 + row) * KD + kt + srcc,
                        (char*)Asl + wv * 1024 + i * 4096);
        }
        #pragma unroll
        for (int i = 0; i < 2; ++i) {            // B: 512 16B-chunks
            int chunk = threadIdx.x + i * 256;
            int row = chunk >> 2, c16 = chunk & 3;
            int srcc = (c16 ^ (row & 3)) * 8;
            gload_lds16(BT + (size_t)(n0 + row) * KD + kt + srcc,
                        (char*)Bsl + wv * 1024 + i * 4096);
        }
        __syncthreads();
        short8 af[AM], bfr[4];
        #pragma unroll
        for (int t = 0; t < AM; ++t) {
            int arow = wm * (BM / 2) + t * 16 + (lane & 15);
            af[t] = ld8(Asl + arow * 32 + (((lane >> 4) * 8) ^ ((arow & 3) * 8)));
        }
        #pragma unroll
        for (int t = 0; t < 4; ++t) {
            int brow = wn * 64 + t * 16 + (lane & 15);
            bfr[t] = ld8(Bsl + brow * 32 + (((lane >> 4) * 8) ^ ((brow & 3) * 8)));
        }
        #pragma unroll
        for (int mt = 0; mt < AM; ++mt)
            #pragma unroll
            for (int nt = 0; nt < 4; ++nt)
                acc[mt][nt] = __builtin_amdgcn_mfma_f32_16x16x32_bf16(af[mt], bfr[nt], acc[mt][nt], 0, 0, 0);
    }

    #pragma unroll
    for (int mt = 0; mt < AM; ++mt) {
        #pragma unroll
        for (int nt = 0; nt < 4; ++nt) {
            #pragma unroll
            for (int r = 0; r < 4; ++r) {
                int row = m0 + wm * (BM / 2) + mt * 16 + (lane >> 4) * 4 + r;
                int col = n0 + wn * 64 + nt * 16 + (lane & 15);
                float v = acc[mt][nt][r];
                if (MODE == 0) {
                    int mat = col >> 8;
                    int cc = col & 255;
                    int hh = cc >> 6, dd = cc & 63;
                    int bbi = row >> 12, nni = row & 4095;
                    int bh = bbi * Hh + hh;
                    // q pre-scaled by 0.125*log2(e) for exp2-domain flash attention
                    if (mat == 0)      o0[((size_t)bh * Nn + nni) * HDd + dd] = f2bf((v + bias0[cc]) * QSCALE);
                    else if (mat == 1) o1[((size_t)bh * Nn + nni) * HDd + dd] = f2bf(v + bias1[cc]);
                    else               o2[((size_t)bh * HDd + dd) * Nn + nni] = f2bf(v + bias2[cc]);
                } else if (MODE == 2) {
                    float xg = v + bias0[col];
                    float g = 0.5f * xg * (1.0f + erff(xg * 0.70710678118654752f));
                    o0[(size_t)row * FFf + col] = f2bf(g);
                } else {
                    outf[(size_t)row * Dd + col] = resid[(size_t)row * Dd + col] + v + bias0[col];
                }
            }
        }
    }
}

// ---------------- out-proj + residual + LayerNorm2, merge fused ----------------
// Each block owns 32 full token rows. The attention A-tile is built directly
// from the KV-split partials (pc/pm/pl): per-(row,head) combine weights, then
// per-column streaming combine into a full bf16 A tile in LDS (written with
// the inverse of the gemm read-swizzle). Eliminates the merge kernel + the
// ctx round-trip entirely.
__global__ __launch_bounds__(256) void oproj_ln_kernel(
        const u16* __restrict__ pc, const float* __restrict__ pm,
        const float* __restrict__ pl, const u16* __restrict__ BT,
        const float* __restrict__ bias, const float* __restrict__ resid,
        const float* __restrict__ lnw, const float* __restrict__ lnb,
        float* __restrict__ x2, u16* __restrict__ yln) {
    __shared__ u16 Asl[8][32 * 32];      // [kchunk][row*32 + swizzled col]
    __shared__ u16 Bsl[256 * 32];
    __shared__ float xlds[32][256];
    __shared__ float f0a[32][4], f1a[32][4];
    int lane = threadIdx.x & 63;
    int wv = threadIdx.x >> 6;
    int m0 = blockIdx.x * 32;
    int b = m0 >> 12;
    int n0 = m0 & 4095;

    // merge weights per (row, head): exact 2-way softmax-partial combine
    if (threadIdx.x < 128) {
        int i = threadIdx.x >> 2, h = threadIdx.x & 3;
        int bh = b * 4 + h;
        int n = n0 + i;
        float m0v = pm[(size_t)bh * Nn + n];
        float m1v = pm[(size_t)(16 + bh) * Nn + n];
        float l0 = pl[(size_t)bh * Nn + n];
        float l1 = pl[(size_t)(16 + bh) * Nn + n];
        float M = fmaxf(m0v, m1v);
        float w0 = fexp2(m0v - M), w1 = fexp2(m1v - M);
        float inv = 1.0f / (l0 * w0 + l1 * w1);
        f0a[i][h] = w0 * inv;
        f1a[i][h] = w1 * inv;
    }
    __syncthreads();

    // build full A tile [32 rows][256 cols]: thread t owns column t
    {
        int c = threadIdx.x;
        int h = c >> 6, d = c & 63;
        int bh = b * 4 + h;
        const u16* p0 = pc + ((size_t)bh * 64 + d) * Nn + n0;
        const u16* p1 = pc + ((size_t)(16 + bh) * 64 + d) * Nn + n0;
        int chunk = c >> 5, cc = c & 31;
        u16* dst = &Asl[chunk][0];
        #pragma unroll
        for (int i0 = 0; i0 < 32; i0 += 8) {
            short8 v0 = ld8(p0 + i0);
            short8 v1 = ld8(p1 + i0);
            #pragma unroll
            for (int j = 0; j < 8; ++j) {
                int i = i0 + j;
                float c0 = __uint_as_float((u32)(unsigned short)v0[j] << 16);
                float c1 = __uint_as_float((u32)(unsigned short)v1[j] << 16);
                float v = c0 * f0a[i][h] + c1 * f1a[i][h];
                // inverse of gemm read-swizzle: col cc -> slot ((cc>>3)^(i&3))*8 + (cc&7)
                dst[i * 32 + (((cc >> 3) ^ (i & 3)) * 8) + (cc & 7)] = f2bf(v);
            }
        }
    }

    f32x4 zz; zz[0] = 0.f; zz[1] = 0.f; zz[2] = 0.f; zz[3] = 0.f;
    f32x4 acc[2][4];
    #pragma unroll
    for (int i = 0; i < 2; ++i)
        #pragma unroll
        for (int j = 0; j < 4; ++j) acc[i][j] = zz;

    for (int kt = 0; kt < Dd; kt += 32) {
        __syncthreads();                         // (also covers A build at kt=0)
        #pragma unroll
        for (int i = 0; i < 4; ++i) {            // B: 1024 16B-chunks (all 256 rows)
            int chunk = threadIdx.x + i * 256;
            int row = chunk >> 2, c16 = chunk & 3;
            int srcc = (c16 ^ (row & 3)) * 8;
            gload_lds16(BT + (size_t)row * Dd + kt + srcc,
                        (char*)Bsl + wv * 1024 + i * 4096);
        }
        __syncthreads();
        short8 af[2], bfr[4];
        const u16* Ac = &Asl[kt >> 5][0];
        #pragma unroll
        for (int t = 0; t < 2; ++t) {
            int arow = t * 16 + (lane & 15);
            af[t] = ld8(Ac + arow * 32 + (((lane >> 4) * 8) ^ ((arow & 3) * 8)));
        }
        #pragma unroll
        for (int t = 0; t < 4; ++t) {
            int brow = wv * 64 + t * 16 + (lane & 15);
            bfr[t] = ld8(Bsl + brow * 32 + (((lane >> 4) * 8) ^ ((brow & 3) * 8)));
        }
        #pragma unroll
        for (int mt = 0; mt < 2; ++mt)
            #pragma unroll
            for (int nt = 0; nt < 4; ++nt)
                acc[mt][nt] = __builtin_amdgcn_mfma_f32_16x16x32_bf16(af[mt], bfr[nt], acc[mt][nt], 0, 0, 0);
    }

    // epilogue: x2 = resid + acc + bias -> global + LDS
    #pragma unroll
    for (int mt = 0; mt < 2; ++mt) {
        #pragma unroll
        for (int nt = 0; nt < 4; ++nt) {
            #pragma unroll
            for (int r = 0; r < 4; ++r) {
                int row = mt * 16 + (lane >> 4) * 4 + r;
                int col = wv * 64 + nt * 16 + (lane & 15);
                float v = resid[(size_t)(m0 + row) * Dd + col] + acc[mt][nt][r] + bias[col];
                x2[(size_t)(m0 + row) * Dd + col] = v;
                xlds[row][col] = v;
            }
        }
    }
    __syncthreads();

    // LN over full rows: 8 threads/row, 32 cols each
    int rw = threadIdx.x >> 3;
    int cg = (threadIdx.x & 7) * 32;
    float s = 0.f, s2 = 0.f;
    #pragma unroll
    for (int j = 0; j < 32; ++j) {
        float v = xlds[rw][cg + j];
        s += v; s2 += v * v;
    }
    #pragma unroll
    for (int off = 1; off < 8; off <<= 1) {
        s  += __shfl_xor(s, off);
        s2 += __shfl_xor(s2, off);
    }
    float mu = s * (1.0f / Dd);
    float var = s2 * (1.0f / Dd) - mu * mu;
    float rstd = rsqrtf(var + 1e-5f);
    u16* op = yln + (size_t)(m0 + rw) * Dd + cg;
    #pragma unroll
    for (int j = 0; j < 32; j += 8) {
        float v0 = (xlds[rw][cg + j + 0] - mu) * rstd * lnw[cg + j + 0] + lnb[cg + j + 0];
        float v1 = (xlds[rw][cg + j + 1] - mu) * rstd * lnw[cg + j + 1] + lnb[cg + j + 1];
        float v2 = (xlds[rw][cg + j + 2] - mu) * rstd * lnw[cg + j + 2] + lnb[cg + j + 2];
        float v3 = (xlds[rw][cg + j + 3] - mu) * rstd * lnw[cg + j + 3] + lnb[cg + j + 3];
        float v4 = (xlds[rw][cg + j + 4] - mu) * rstd * lnw[cg + j + 4] + lnb[cg + j + 4];
        float v5 = (xlds[rw][cg + j + 5] - mu) * rstd * lnw[cg + j + 5] + lnb[cg + j + 5];
        float v6 = (xlds[rw][cg + j + 6] - mu) * rstd * lnw[cg + j + 6] + lnb[cg + j + 6];
        float v7 = (xlds[rw][cg + j + 7] - mu) * rstd * lnw[cg + j + 7] + lnb[cg + j + 7];
        uint4 pk;
        pk.x = cvtpk(v0, v1); pk.y = cvtpk(v2, v3);
        pk.z = cvtpk(v4, v5); pk.w = cvtpk(v6, v7);
        *(uint4*)(op + j) = pk;
    }
}

// ---------------- Flash attention, KV-split x2, 2-qset waves ----------------
// grid: 2 halves x 16 bh x 16 qt(256). 4 waves x 64 q-rows (two 32-q sets).
// K/V frags load once per tile, feed both qsets (halves LDS reads per q);
// qsetA softmax overlaps qsetB QK^T (in-wave ILP). Single lacc via row-split
// all-ones A-frags (rows 0-15 = qsetA sums, rows 16-31 = qsetB).
__global__ __launch_bounds__(256, 2) void attn_kernel(
        const u16* __restrict__ Qb, const u16* __restrict__ Kb,
        const u16* __restrict__ VTb, const u32* __restrict__ impPk,
        u16* __restrict__ pc, float* __restrict__ pm, float* __restrict__ pl) {
    __shared__ u16 Klds[2][64 * 64];
    __shared__ u16 Vlds[2][64 * 64];
    int lane = threadIdx.x & 63;
    int wv = threadIdx.x >> 6;
    int kvh = blockIdx.x >> 8;
    int bh = (blockIdx.x >> 4) & 15;
    int qt = blockIdx.x & 15;
    int bbi = bh >> 2;
    int qrow0 = qt * 256 + wv * 64;
    int q = lane & 31;
    int hf = lane >> 5;
    int key0 = kvh * 2048;
    int pg = kvh * 16 + bh;

    // Q B-frags, two qsets
    short8 qfA[4], qfB[4];
    #pragma unroll
    for (int ks = 0; ks < 4; ++ks) {
        qfA[ks] = ld8(Qb + ((size_t)bh * Nn + qrow0 + q) * HDd + ks * 16 + hf * 8);
        qfB[ks] = ld8(Qb + ((size_t)bh * Nn + qrow0 + 32 + q) * HDd + ks * 16 + hf * 8);
    }

    // B-frag with ones at k=0,1 (importance augmentation)
    short8 onef = (short8)0;
    if (hf == 0) { onef[0] = (short)0x3F80; onef[1] = (short)0x3F80; }
    // row-split all-ones A-frags: aoneLo -> rows 0-15 (qsetA), aoneHi -> 16-31
    short8 aoneLo = (short8)0, aoneHi = (short8)0;
    if ((lane & 31) < 16) {
        #pragma unroll
        for (int j = 0; j < 8; ++j) aoneLo[j] = (short)0x3F80;
    } else {
        #pragma unroll
        for (int j = 0; j < 8; ++j) aoneHi[j] = (short)0x3F80;
    }

    // staging: lane covers LDS row base+(l>>3), slot l&7; source pre-swizzled
    int sr = lane >> 3;
    int sc = lane & 7;
    int swz = (sc ^ sr) * 8;
    const u16* kp = Kb + ((size_t)bh * Nn + key0 + wv * 16 + sr) * HDd + swz;
    const u16* vp = VTb + ((size_t)bh * HDd + wv * 16 + sr) * Nn + key0 + swz;
    size_t ib = (size_t)bbi * Nn;

    gload_lds16(kp,           (char*)Klds[0] + wv * 2048);
    gload_lds16(kp + 8 * HDd, (char*)Klds[0] + wv * 2048 + 1024);
    gload_lds16(vp,           (char*)Vlds[0] + wv * 2048);
    gload_lds16(vp + 8 * Nn,  (char*)Vlds[0] + wv * 2048 + 1024);
    kp += 64 * HDd; vp += 64;
    u32 npk0 = impPk[ib + key0 + q], npk1 = impPk[ib + key0 + 32 + q];

    f32x16 ctxA[2], ctxB[2], lacc;
    #pragma unroll
    for (int r = 0; r < 16; ++r) {
        ctxA[0][r] = 0.f; ctxA[1][r] = 0.f;
        ctxB[0][r] = 0.f; ctxB[1][r] = 0.f;
        lacc[r] = 0.f;
    }
    float mA = -__builtin_inff(), mB = -__builtin_inff();

    int cur = 0;
    for (int t = 0; t < 32; ++t) {
        __syncthreads();   // buf[cur] ready; buf[cur^1] free
        u32 pk0 = npk0, pk1 = npk1;
        if (t < 31) {
            gload_lds16(kp,           (char*)Klds[cur ^ 1] + wv * 2048);
            gload_lds16(kp + 8 * HDd, (char*)Klds[cur ^ 1] + wv * 2048 + 1024);
            gload_lds16(vp,           (char*)Vlds[cur ^ 1] + wv * 2048);
            gload_lds16(vp + 8 * Nn,  (char*)Vlds[cur ^ 1] + wv * 2048 + 1024);
            kp += 64 * HDd; vp += 64;
            npk0 = impPk[ib + key0 + t * 64 + 64 + q];
            npk1 = impPk[ib + key0 + t * 64 + 96 + q];
        }
        const u16* Kc = Klds[cur];
        const u16* Vc = Vlds[cur];

        // ---- QK^T: K-frags shared across both qsets ----
        f32x16 sA0, sA1, sB0, sB1;
        #pragma unroll
        for (int r = 0; r < 16; ++r) { sA0[r] = 0.f; sA1[r] = 0.f; sB0[r] = 0.f; sB1[r] = 0.f; }
        __builtin_amdgcn_s_setprio(1);
        #pragma unroll
        for (int ks = 0; ks < 4; ++ks) {
            short8 kf0 = ld8(Kc + q * 64 + (((ks * 2 + hf) ^ (q & 7)) * 8));
            short8 kf1 = ld8(Kc + (32 + q) * 64 + (((ks * 2 + hf) ^ (q & 7)) * 8));
            sA0 = __builtin_amdgcn_mfma_f32_32x32x16_bf16(kf0, qfA[ks], sA0, 0, 0, 0);
            sA1 = __builtin_amdgcn_mfma_f32_32x32x16_bf16(kf1, qfA[ks], sA1, 0, 0, 0);
            sB0 = __builtin_amdgcn_mfma_f32_32x32x16_bf16(kf0, qfB[ks], sB0, 0, 0, 0);
            sB1 = __builtin_amdgcn_mfma_f32_32x32x16_bf16(kf1, qfB[ks], sB1, 0, 0, 0);
        }
        short8 af0 = (short8)0, af1 = (short8)0;
        if (hf == 0) {
            af0[0] = (short)(pk0 & 0xFFFFu); af0[1] = (short)(pk0 >> 16);
            af1[0] = (short)(pk1 & 0xFFFFu); af1[1] = (short)(pk1 >> 16);
        }
        sA0 = __builtin_amdgcn_mfma_f32_32x32x16_bf16(af0, onef, sA0, 0, 0, 0);
        sA1 = __builtin_amdgcn_mfma_f32_32x32x16_bf16(af1, onef, sA1, 0, 0, 0);
        sB0 = __builtin_amdgcn_mfma_f32_32x32x16_bf16(af0, onef, sB0, 0, 0, 0);
        sB1 = __builtin_amdgcn_mfma_f32_32x32x16_bf16(af1, onef, sB1, 0, 0, 0);
        __builtin_amdgcn_s_setprio(0);

        // ---- softmax qsetA ----
        {
            float a0 = max3f(sA0[0], sA0[1], sA0[2]);
            float a1 = max3f(sA0[3], sA0[4], sA0[5]);
            float a2 = max3f(sA0[6], sA0[7], sA0[8]);
            float a3 = max3f(sA0[9], sA0[10], sA0[11]);
            float a4 = max3f(sA0[12], sA0[13], sA0[14]);
            float b0 = max3f(sA1[0], sA1[1], sA1[2]);
            float b1 = max3f(sA1[3], sA1[4], sA1[5]);
            float b2 = max3f(sA1[6], sA1[7], sA1[8]);
            float b3 = max3f(sA1[9], sA1[10], sA1[11]);
            float b4 = max3f(sA1[12], sA1[13], sA1[14]);
            float c0 = max3f(a0, a1, a2);
            float c1 = max3f(a3, a4, sA0[15]);
            float c2 = max3f(b0, b1, b2);
            float c3 = max3f(b3, b4, sA1[15]);
            float tm = xhalf_max(fmaxf(max3f(c0, c1, c2), c3));
            bool nore = __all(tm <= mA + 8.0f);
            if (!nore) {
                float nm = fmaxf(mA, tm);
                float al = fexp2(mA - nm);
                #pragma unroll
                for (int r = 0; r < 8; ++r) lacc[r] *= al;   // qsetA rows 0-15
                #pragma unroll
                for (int r = 0; r < 16; ++r) { ctxA[0][r] *= al; ctxA[1][r] *= al; }
                mA = nm;
            }
            #pragma unroll
            for (int r = 0; r < 16; ++r) { sA0[r] = fexp2(sA0[r] - mA); sA1[r] = fexp2(sA1[r] - mA); }
        }
        // ---- softmax qsetB ----
        {
            float a0 = max3f(sB0[0], sB0[1], sB0[2]);
            float a1 = max3f(sB0[3], sB0[4], sB0[5]);
            float a2 = max3f(sB0[6], sB0[7], sB0[8]);
            float a3 = max3f(sB0[9], sB0[10], sB0[11]);
            float a4 = max3f(sB0[12], sB0[13], sB0[14]);
            float b0 = max3f(sB1[0], sB1[1], sB1[2]);
            float b1 = max3f(sB1[3], sB1[4], sB1[5]);
            float b2 = max3f(sB1[6], sB1[7], sB1[8]);
            float b3 = max3f(sB1[9], sB1[10], sB1[11]);
            float b4 = max3f(sB1[12], sB1[13], sB1[14]);
            float c0 = max3f(a0, a1, a2);
            float c1 = max3f(a3, a4, sB0[15]);
            float c2 = max3f(b0, b1, b2);
            float c3 = max3f(b3, b4, sB1[15]);
            float tm = xhalf_max(fmaxf(max3f(c0, c1, c2), c3));
            bool nore = __all(tm <= mB + 8.0f);
            if (!nore) {
                float nm = fmaxf(mB, tm);
                float al = fexp2(mB - nm);
                #pragma unroll
                for (int r = 8; r < 16; ++r) lacc[r] *= al;  // qsetB rows 16-31
                #pragma unroll
                for (int r = 0; r < 16; ++r) { ctxB[0][r] *= al; ctxB[1][r] *= al; }
                mB = nm;
            }
            #pragma unroll
            for (int r = 0; r < 16; ++r) { sB0[r] = fexp2(sB0[r] - mB); sB1[r] = fexp2(sB1[r] - mB); }
        }

        // ---- P -> bf16 B-frags in-register (both qsets) ----
        u32 wA0[8], wA1[8], wB0[8], wB1[8];
        #pragma unroll
        for (int j = 0; j < 8; ++j) {
            wA0[j] = cvtpk(sA0[2 * j], sA0[2 * j + 1]);
            wA1[j] = cvtpk(sA1[2 * j], sA1[2 * j + 1]);
            wB0[j] = cvtpk(sB0[2 * j], sB0[2 * j + 1]);
            wB1[j] = cvtpk(sB1[2 * j], sB1[2 * j + 1]);
        }
        pl32swap(wA0[0], wA0[2]); pl32swap(wA0[1], wA0[3]);
        pl32swap(wA0[4], wA0[6]); pl32swap(wA0[5], wA0[7]);
        pl32swap(wA1[0], wA1[2]); pl32swap(wA1[1], wA1[3]);
        pl32swap(wA1[4], wA1[6]); pl32swap(wA1[5], wA1[7]);
        pl32swap(wB0[0], wB0[2]); pl32swap(wB0[1], wB0[3]);
        pl32swap(wB0[4], wB0[6]); pl32swap(wB0[5], wB0[7]);
        pl32swap(wB1[0], wB1[2]); pl32swap(wB1[1], wB1[3]);
        pl32swap(wB1[4], wB1[6]); pl32swap(wB1[5], wB1[7]);
        short8 pfA[4], pfB[4];
        {
            u32x4 t0; t0[0] = wA0[0]; t0[1] = wA0[1]; t0[2] = wA0[2]; t0[3] = wA0[3];
            u32x4 t1; t1[0] = wA0[4]; t1[1] = wA0[5]; t1[2] = wA0[6]; t1[3] = wA0[7];
            u32x4 t2; t2[0] = wA1[0]; t2[1] = wA1[1]; t2[2] = wA1[2]; t2[3] = wA1[3];
            u32x4 t3; t3[0] = wA1[4]; t3[1] = wA1[5]; t3[2] = wA1[6]; t3[3] = wA1[7];
            pfA[0] = __builtin_bit_cast(short8, t0);
            pfA[1] = __builtin_bit_cast(short8, t1);
            pfA[2] = __builtin_bit_cast(short8, t2);
            pfA[3] = __builtin_bit_cast(short8, t3);
            u32x4 u0; u0[0] = wB0[0]; u0[1] = wB0[1]; u0[2] = wB0[2]; u0[3] = wB0[3];
            u32x4 u1; u1[0] = wB0[4]; u1[1] = wB0[5]; u1[2] = wB0[6]; u1[3] = wB0[7];
            u32x4 u2; u2[0] = wB1[0]; u2[1] = wB1[1]; u2[2] = wB1[2]; u2[3] = wB1[3];
            u32x4 u3; u3[0] = wB1[4]; u3[1] = wB1[5]; u3[2] = wB1[6]; u3[3] = wB1[7];
            pfB[0] = __builtin_bit_cast(short8, u0);
            pfB[1] = __builtin_bit_cast(short8, u1);
            pfB[2] = __builtin_bit_cast(short8, u2);
            pfB[3] = __builtin_bit_cast(short8, u3);
        }

        // ---- PV + l-accumulation: V-frags shared across qsets ----
        __builtin_amdgcn_s_setprio(1);
        #pragma unroll
        for (int j = 0; j < 4; ++j) {
            lacc = __builtin_amdgcn_mfma_f32_32x32x16_bf16(aoneLo, pfA[j], lacc, 0, 0, 0);
            lacc = __builtin_amdgcn_mfma_f32_32x32x16_bf16(aoneHi, pfB[j], lacc, 0, 0, 0);
        }
        #pragma unroll
        for (int dt = 0; dt < 2; ++dt) {
            int vrow = dt * 32 + q;
            const u16* vb = Vc + vrow * 64;
            int sw = vrow & 7;
            #pragma unroll
            for (int j = 0; j < 4; ++j) {
                short8 vf = ld8(vb + (((2 * j + hf) ^ sw) * 8));
                ctxA[dt] = __builtin_amdgcn_mfma_f32_32x32x16_bf16(vf, pfA[j], ctxA[dt], 0, 0, 0);
                ctxB[dt] = __builtin_amdgcn_mfma_f32_32x32x16_bf16(vf, pfB[j], ctxB[dt], 0, 0, 0);
            }
        }
        __builtin_amdgcn_s_setprio(0);
        cur ^= 1;
    }

    // ---- epilogue: write unnormalized partials (both qsets) ----
    int qgA = qrow0 + q, qgB = qrow0 + 32 + q;
    if (hf == 0) {
        pm[(size_t)pg * Nn + qgA] = mA;
        pl[(size_t)pg * Nn + qgA] = lacc[0];   // qsetA rows 0-15
        pm[(size_t)pg * Nn + qgB] = mB;
        pl[(size_t)pg * Nn + qgB] = lacc[8];   // qsetB rows 16-31
    }
    #pragma unroll
    for (int dt = 0; dt < 2; ++dt) {
        #pragma unroll
        for (int r = 0; r < 16; ++r) {
            int d = dt * 32 + (r & 3) + 8 * (r >> 2) + 4 * hf;
            pc[((size_t)pg * 64 + d) * Nn + qgA] = f2bf(ctxA[dt][r]);
            pc[((size_t)pg * 64 + d) * Nn + qgB] = f2bf(ctxB[dt][r]);
        }
    }
}

extern "C" void kernel_launch(void* const* d_in, const int* in_sizes, int n_in,
                              void* d_out, int out_size, void* d_ws, size_t ws_size,
                              hipStream_t stream) {
    (void)in_sizes; (void)n_in; (void)out_size; (void)ws_size;
    const float* tokens     = (const float*)d_in[0];
    const float* importance = (const float*)d_in[1];
    const float* n1w = (const float*)d_in[2];
    const float* n1b = (const float*)d_in[3];
    const float* Wq  = (const float*)d_in[4];
    const float* bq  = (const float*)d_in[5];
    const float* Wk  = (const float*)d_in[6];
    const float* bk  = (const float*)d_in[7];
    const float* Wv  = (const float*)d_in[8];
    const float* bv  = (const float*)d_in[9];
    const float* Wo  = (const float*)d_in[10];
    const float* bo  = (const float*)d_in[11];
    const float* n2w = (const float*)d_in[12];
    const float* n2b = (const float*)d_in[13];
    const float* W1  = (const float*)d_in[14];
    const float* b1  = (const float*)d_in[15];
    const float* W2  = (const float*)d_in[16];
    const float* b2  = (const float*)d_in[17];
    float* out = (float*)d_out;

    char* ws = (char*)d_ws;
    const size_t MB = (size_t)1 << 20;
    // Sequential reuse (single stream): yln reuses xln (dead after QKV GEMM);
    // hbuf reuses qb+kb (dead after attn); x2 = d_out (dead until out-proj).
    u16* xln   = (u16*)(ws);                    // 0..8MB   (later: yln)
    u16* qb    = (u16*)(ws + 8 * MB);           // 8..16MB  (later: hbuf lo)
    u16* kb    = (u16*)(ws + 16 * MB);          // 16..24MB (later: hbuf hi)
    u16* vT    = (u16*)(ws + 24 * MB);          // 24..32MB
    u16* pc    = (u16*)(ws + 40 * MB);          // 40..56MB [kvh*16+bh][64 d][4096 q]
    float* pm  = (float*)(ws + 56 * MB);        // 512KB
    float* pl  = (float*)(ws + 56 * MB + 524288);
    u16* WqkvT = (u16*)(ws + 57 * MB);          // 384KB
    u16* WoT   = (u16*)(ws + 57 * MB + 393216);
    u16* W1T   = (u16*)(ws + 57 * MB + 393216 + 131072);
    u16* W2T   = (u16*)(ws + 57 * MB + 393216 + 131072 + 262144);
    u32* impPk = (u32*)(ws + 57 * MB + 393216 + 131072 + 262144 + 262144);
    u16* yln   = xln;                           // reuse (xln dead after QKV)
    u16* hbuf  = qb;                            // reuse 16MB (qb+kb dead after attn)
    float* x2  = out;                           // reuse d_out as x2 scratch

    prep_kernel<<<2112, 256, 0, stream>>>(Wq, Wk, Wv, Wo, W1, W2, importance,
                                          WqkvT, WoT, W1T, W2T, impPk);
    ln_kernel<<<4096, 256, 0, stream>>>(tokens, n1w, n1b, xln);
    gemm_bt<0, 256, 128><<<dim3(6, 128), 256, 0, stream>>>(xln, WqkvT, bq, bk, bv,
                                                           nullptr, nullptr, qb, kb, vT);
    attn_kernel<<<512, 256, 0, stream>>>(qb, kb, vT, impPk, pc, pm, pl);
    oproj_ln_kernel<<<512, 256, 0, stream>>>(pc, pm, pl, WoT, bo, tokens,
                                             n2w, n2b, x2, yln);
    gemm_bt<2, 256, 64><<<dim3(4, 256), 256, 0, stream>>>(yln, W1T, b1, nullptr, nullptr,
                                                          nullptr, nullptr, hbuf, nullptr, nullptr);
    gemm_bt<3, 512, 64><<<dim3(2, 256), 256, 0, stream>>>(hbuf, W2T, b2, nullptr, nullptr,
                                                          x2, out, nullptr, nullptr, nullptr);
}